// Round 1
// baseline (1584.036 us; speedup 1.0000x reference)
//
#include <hip/hip_runtime.h>
#include <hip/hip_bf16.h>
#include <math.h>

#define B_    2
#define N_    2048
#define DIM_  1024
#define H_    16
#define HD_   64
#define EPS_  1e-5f
#define SCALE_ 0.125f   // HD_^-0.5

// ---------------------------------------------------------------------------
// Generic NT GEMM: C[M,Ncols] = A[M,K] * B[Ncols,K]^T (+ bias)
// A_IS_BHND: A logical row r=(b*N_+n), col k=(h*64+d) gathered from
//            (B,H,N,D)-layout buffer (attention output).
// 64x64 tile, TK=32, 256 threads, 4x4 accum per thread.
// ---------------------------------------------------------------------------
template <int WITH_BIAS, int A_IS_BHND>
__global__ __launch_bounds__(256) void gemm_nt(const float* __restrict__ A,
                                               const float* __restrict__ Bw,
                                               const float* __restrict__ bias,
                                               float* __restrict__ C,
                                               int M, int Ncols, int K) {
    __shared__ float As[64][33];
    __shared__ float Bs[64][33];
    const int tid = threadIdx.x;
    const int tx = tid & 15, ty = tid >> 4;
    const int row0 = blockIdx.y * 64, col0 = blockIdx.x * 64;

    float acc[16];
#pragma unroll
    for (int i = 0; i < 16; ++i) acc[i] = 0.f;

    for (int k0 = 0; k0 < K; k0 += 32) {
#pragma unroll
        for (int i = 0; i < 8; ++i) {
            int idx = tid + i * 256;          // 0..2047
            int r = idx >> 5, kk = idx & 31;  // 64 rows x 32 k
            float av;
            if (A_IS_BHND) {
                int grow = row0 + r;          // b*N_+n
                int gk = k0 + kk;             // h*64+d
                int bb_ = grow >> 11, n = grow & (N_ - 1);
                int h = gk >> 6, d = gk & 63;
                av = A[(((size_t)(bb_ * H_ + h) * N_) + n) * 64 + d];
            } else {
                av = A[(size_t)(row0 + r) * K + k0 + kk];
            }
            As[r][kk] = av;
            Bs[r][kk] = Bw[(size_t)(col0 + r) * K + k0 + kk];
        }
        __syncthreads();
#pragma unroll 8
        for (int kk = 0; kk < 32; ++kk) {
            float a[4], breg[4];
#pragma unroll
            for (int i = 0; i < 4; ++i) a[i] = As[ty * 4 + i][kk];
#pragma unroll
            for (int j = 0; j < 4; ++j) breg[j] = Bs[tx * 4 + j][kk];
#pragma unroll
            for (int i = 0; i < 4; ++i)
#pragma unroll
                for (int j = 0; j < 4; ++j) acc[i * 4 + j] += a[i] * breg[j];
        }
        __syncthreads();
    }
#pragma unroll
    for (int i = 0; i < 4; ++i) {
        int r = row0 + ty * 4 + i;
#pragma unroll
        for (int j = 0; j < 4; ++j) {
            int c = col0 + tx * 4 + j;
            float v = acc[i * 4 + j];
            if (WITH_BIAS) v += bias[c];
            C[(size_t)r * Ncols + c] = v;
        }
    }
}

// ---------------------------------------------------------------------------
// LayerNorm(q), LayerNorm(k), scale(q), and split qkv (B,N,3,H,D) into
// (B,H,N,D) q/k/v buffers. One wave (64 lanes) per (b,n,t,h) group.
// ---------------------------------------------------------------------------
__global__ __launch_bounds__(256) void qkv_norm_split(
    const float* __restrict__ qkv, const float* __restrict__ qw,
    const float* __restrict__ qb, const float* __restrict__ kw,
    const float* __restrict__ kb, float* __restrict__ qo,
    float* __restrict__ ko, float* __restrict__ vo) {
    int wid = blockIdx.x * 4 + (threadIdx.x >> 6);  // ((b*N_+n)*3+t)*H_+h
    int lane = threadIdx.x & 63;
    int h = wid % H_;
    int t = (wid / H_) % 3;
    int bn = wid / (H_ * 3);
    int n = bn & (N_ - 1);
    int b = bn >> 11;
    float val = qkv[(size_t)wid * 64 + lane];
    size_t oidx = ((size_t)(b * H_ + h) * N_ + n) * 64 + lane;
    if (t == 2) {  // wave-uniform branch
        vo[oidx] = val;
        return;
    }
    float s = val;
#pragma unroll
    for (int off = 32; off > 0; off >>= 1) s += __shfl_xor(s, off);
    float mu = s * (1.f / 64.f);
    float d = val - mu;
    float s2 = d * d;
#pragma unroll
    for (int off = 32; off > 0; off >>= 1) s2 += __shfl_xor(s2, off);
    float r = rsqrtf(s2 * (1.f / 64.f) + EPS_);
    if (t == 0) {
        qo[oidx] = (d * r * qw[lane] + qb[lane]) * SCALE_;
    } else {
        ko[oidx] = d * r * kw[lane] + kb[lane];
    }
}

// ---------------------------------------------------------------------------
// Flash attention, fp32 scalar. Block = 256 threads, one (b,h) x 64-row
// Q-tile per block; K/V tiles of 64 keys streamed through LDS with online
// softmax. mask (B,1,N,N) int32, nonzero = masked out.
// ---------------------------------------------------------------------------
__global__ __launch_bounds__(256) void flash_attn(
    const float* __restrict__ q, const float* __restrict__ k,
    const float* __restrict__ v, const int* __restrict__ mask,
    float* __restrict__ ao) {
    __shared__ float Qs[64][65];
    __shared__ float Ks[64][65];
    __shared__ float Vs[64][65];
    __shared__ float Ss[64][65];
    __shared__ float m_s[64], l_s[64], al_s[64];
    const int tid = threadIdx.x;
    const int tx = tid & 15, ty = tid >> 4;
    const int bh = blockIdx.y;  // b*H_+h
    const int b = bh >> 4;
    const int q0 = blockIdx.x * 64;

    const float* qp = q + ((size_t)bh * N_ + q0) * 64;
#pragma unroll
    for (int i = 0; i < 16; ++i) {
        int idx = i * 256 + tid;
        Qs[idx >> 6][idx & 63] = qp[idx];
    }
    if (tid < 64) {
        m_s[tid] = -3.0e38f;
        l_s[tid] = 0.f;
    }
    float o[16];
#pragma unroll
    for (int i = 0; i < 16; ++i) o[i] = 0.f;

    const int* mbase = mask + (size_t)b * N_ * N_;

    for (int k0 = 0; k0 < N_; k0 += 64) {
        __syncthreads();  // protect Ks/Vs/Ss reuse
        const float* kp = k + ((size_t)bh * N_ + k0) * 64;
        const float* vp = v + ((size_t)bh * N_ + k0) * 64;
#pragma unroll
        for (int i = 0; i < 16; ++i) {
            int idx = i * 256 + tid;
            int r = idx >> 6, c = idx & 63;
            Ks[r][c] = kp[idx];
            Vs[r][c] = vp[idx];
        }
        __syncthreads();

        // S = Q K^T (64x64)
        float sv[16];
#pragma unroll
        for (int i = 0; i < 16; ++i) sv[i] = 0.f;
        for (int kk = 0; kk < 64; ++kk) {
            float a[4], bb[4];
#pragma unroll
            for (int i = 0; i < 4; ++i) a[i] = Qs[ty * 4 + i][kk];
#pragma unroll
            for (int j = 0; j < 4; ++j) bb[j] = Ks[tx * 4 + j][kk];
#pragma unroll
            for (int i = 0; i < 4; ++i)
#pragma unroll
                for (int j = 0; j < 4; ++j) sv[i * 4 + j] += a[i] * bb[j];
        }
        // mask + stash S in LDS
#pragma unroll
        for (int i = 0; i < 4; ++i) {
            int gr = q0 + ty * 4 + i;
            const int* mp = mbase + (size_t)gr * N_ + k0 + tx * 4;
#pragma unroll
            for (int j = 0; j < 4; ++j) {
                float s = sv[i * 4 + j];
                if (mp[j] != 0) s = -1e30f;
                Ss[ty * 4 + i][tx * 4 + j] = s;
            }
        }
        __syncthreads();

        // online softmax row update (64 threads, one row each)
        if (tid < 64) {
            float mold = m_s[tid];
            float mnew = mold;
            for (int c = 0; c < 64; ++c) mnew = fmaxf(mnew, Ss[tid][c]);
            float alpha = __expf(mold - mnew);
            float l = l_s[tid] * alpha;
            for (int c = 0; c < 64; ++c) {
                float p = __expf(Ss[tid][c] - mnew);
                Ss[tid][c] = p;
                l += p;
            }
            m_s[tid] = mnew;
            l_s[tid] = l;
            al_s[tid] = alpha;
        }
        __syncthreads();

        // O = O*alpha + P V
#pragma unroll
        for (int i = 0; i < 4; ++i) {
            float alpha = al_s[ty * 4 + i];
#pragma unroll
            for (int j = 0; j < 4; ++j) o[i * 4 + j] *= alpha;
        }
        for (int kk = 0; kk < 64; ++kk) {
            float p[4], vv[4];
#pragma unroll
            for (int i = 0; i < 4; ++i) p[i] = Ss[ty * 4 + i][kk];
#pragma unroll
            for (int j = 0; j < 4; ++j) vv[j] = Vs[kk][tx * 4 + j];
#pragma unroll
            for (int i = 0; i < 4; ++i)
#pragma unroll
                for (int j = 0; j < 4; ++j) o[i * 4 + j] += p[i] * vv[j];
        }
    }
    __syncthreads();
    float* aop = ao + ((size_t)bh * N_ + q0) * 64;
#pragma unroll
    for (int i = 0; i < 4; ++i) {
        float inv = 1.f / l_s[ty * 4 + i];
#pragma unroll
        for (int j = 0; j < 4; ++j)
            aop[(size_t)(ty * 4 + i) * 64 + tx * 4 + j] = o[i * 4 + j] * inv;
    }
}

// ---------------------------------------------------------------------------
extern "C" void kernel_launch(void* const* d_in, const int* in_sizes, int n_in,
                              void* d_out, int out_size, void* d_ws,
                              size_t ws_size, hipStream_t stream) {
    const float* x     = (const float*)d_in[0];
    const int*   mask  = (const int*)d_in[1];
    const float* qkv_w = (const float*)d_in[2];
    const float* qnw   = (const float*)d_in[3];
    const float* qnb   = (const float*)d_in[4];
    const float* knw   = (const float*)d_in[5];
    const float* knb   = (const float*)d_in[6];
    const float* pw    = (const float*)d_in[7];
    const float* pb    = (const float*)d_in[8];
    float* out = (float*)d_out;

    // workspace layout (floats)
    float* ws   = (float*)d_ws;
    float* qkv  = ws;                                  // 4096*3072 = 12.58M
    float* qbuf = qkv + (size_t)4096 * 3072;           // 4.19M each
    float* kbuf = qbuf + (size_t)B_ * H_ * N_ * HD_;
    float* vbuf = kbuf + (size_t)B_ * H_ * N_ * HD_;
    float* ao   = qkv;  // alias: qkv is dead after norm/split

    // 1) qkv = x @ qkv_w^T : (4096,1024) x (3072,1024)^T
    gemm_nt<0, 0><<<dim3(3072 / 64, 4096 / 64), 256, 0, stream>>>(
        x, qkv_w, nullptr, qkv, B_ * N_, 3 * DIM_, DIM_);

    // 2) layernorm q,k + scale + split to (B,H,N,D)
    qkv_norm_split<<<dim3((B_ * N_ * 3 * H_) / 4), 256, 0, stream>>>(
        qkv, qnw, qnb, knw, knb, qbuf, kbuf, vbuf);

    // 3) masked flash attention -> ao (B,H,N,D)
    flash_attn<<<dim3(N_ / 64, B_ * H_), 256, 0, stream>>>(qbuf, kbuf, vbuf,
                                                           mask, ao);

    // 4) out = ao(transposed view) @ proj_w^T + proj_b
    gemm_nt<1, 1><<<dim3(DIM_ / 64, 4096 / 64), 256, 0, stream>>>(
        ao, pw, pb, out, B_ * N_, DIM_, DIM_);
}

// Round 2
// 987.069 us; speedup vs baseline: 1.6048x; 1.6048x over previous
//
#include <hip/hip_runtime.h>
#include <hip/hip_bf16.h>
#include <math.h>

#define B_    2
#define N_    2048
#define DIM_  1024
#define H_    16
#define HD_   64
#define EPS_  1e-5f
#define SCALE_ 0.125f   // HD_^-0.5

typedef __attribute__((ext_vector_type(8))) __bf16 bf16x8;
typedef __attribute__((ext_vector_type(8))) unsigned short ushort8;
typedef __attribute__((ext_vector_type(4))) float f32x4;

__device__ __forceinline__ unsigned short f2bf(float x) {
    unsigned u = __builtin_bit_cast(unsigned, x);
    u += 0x7fff + ((u >> 16) & 1);   // RNE
    return (unsigned short)(u >> 16);
}

__device__ __forceinline__ void gl_lds16(const void* g, void* l) {
    __builtin_amdgcn_global_load_lds(
        (const __attribute__((address_space(1))) void*)g,
        (__attribute__((address_space(3))) void*)l, 16, 0, 0);
}

// ---------------------------------------------------------------------------
// fp32 NT GEMM (unchanged from round 1): C = A * B^T (+bias).
// ---------------------------------------------------------------------------
template <int WITH_BIAS, int A_IS_BHND>
__global__ __launch_bounds__(256) void gemm_nt(const float* __restrict__ A,
                                               const float* __restrict__ Bw,
                                               const float* __restrict__ bias,
                                               float* __restrict__ C,
                                               int M, int Ncols, int K) {
    __shared__ float As[64][33];
    __shared__ float Bs[64][33];
    const int tid = threadIdx.x;
    const int tx = tid & 15, ty = tid >> 4;
    const int row0 = blockIdx.y * 64, col0 = blockIdx.x * 64;

    float acc[16];
#pragma unroll
    for (int i = 0; i < 16; ++i) acc[i] = 0.f;

    for (int k0 = 0; k0 < K; k0 += 32) {
#pragma unroll
        for (int i = 0; i < 8; ++i) {
            int idx = tid + i * 256;
            int r = idx >> 5, kk = idx & 31;
            float av;
            if (A_IS_BHND) {
                int grow = row0 + r;
                int gk = k0 + kk;
                int bb_ = grow >> 11, n = grow & (N_ - 1);
                int h = gk >> 6, d = gk & 63;
                av = A[(((size_t)(bb_ * H_ + h) * N_) + n) * 64 + d];
            } else {
                av = A[(size_t)(row0 + r) * K + k0 + kk];
            }
            As[r][kk] = av;
            Bs[r][kk] = Bw[(size_t)(col0 + r) * K + k0 + kk];
        }
        __syncthreads();
#pragma unroll 8
        for (int kk = 0; kk < 32; ++kk) {
            float a[4], breg[4];
#pragma unroll
            for (int i = 0; i < 4; ++i) a[i] = As[ty * 4 + i][kk];
#pragma unroll
            for (int j = 0; j < 4; ++j) breg[j] = Bs[tx * 4 + j][kk];
#pragma unroll
            for (int i = 0; i < 4; ++i)
#pragma unroll
                for (int j = 0; j < 4; ++j) acc[i * 4 + j] += a[i] * breg[j];
        }
        __syncthreads();
    }
#pragma unroll
    for (int i = 0; i < 4; ++i) {
        int r = row0 + ty * 4 + i;
#pragma unroll
        for (int j = 0; j < 4; ++j) {
            int c = col0 + tx * 4 + j;
            float v = acc[i * 4 + j];
            if (WITH_BIAS) v += bias[c];
            C[(size_t)r * Ncols + c] = v;
        }
    }
}

// ---------------------------------------------------------------------------
// LayerNorm q,k (fp32 math) -> bf16 (B,H,N,D). One wave per (b,n,t,h), t in
// {0,1}. q pre-scaled by D^-0.5 (exact pow2, applied before rounding).
// ---------------------------------------------------------------------------
__global__ __launch_bounds__(256) void qkv_norm_split(
    const float* __restrict__ qkv, const float* __restrict__ qw,
    const float* __restrict__ qb, const float* __restrict__ kw,
    const float* __restrict__ kb, unsigned short* __restrict__ qo,
    unsigned short* __restrict__ ko) {
    int wid = blockIdx.x * 4 + (threadIdx.x >> 6);  // ((b*N+n)*2+t)*H + h
    int lane = threadIdx.x & 63;
    int h = wid & 15;
    int t = (wid >> 4) & 1;
    int bn = wid >> 5;
    int n = bn & (N_ - 1);
    int b = bn >> 11;
    float val = qkv[((size_t)bn * 3 + t) * DIM_ + h * 64 + lane];
    size_t oidx = ((size_t)(b * H_ + h) * N_ + n) * 64 + lane;
    float s = val;
#pragma unroll
    for (int off = 32; off > 0; off >>= 1) s += __shfl_xor(s, off);
    float mu = s * (1.f / 64.f);
    float d = val - mu;
    float s2 = d * d;
#pragma unroll
    for (int off = 32; off > 0; off >>= 1) s2 += __shfl_xor(s2, off);
    float r = rsqrtf(s2 * (1.f / 64.f) + EPS_);
    if (t == 0) {
        qo[oidx] = f2bf((d * r * qw[lane] + qb[lane]) * SCALE_);
    } else {
        ko[oidx] = f2bf(d * r * kw[lane] + kb[lane]);
    }
}

// ---------------------------------------------------------------------------
// Extract V from fp32 qkv, cast bf16, write transposed (B,H,D,N).
// 64(key) x 64(d) tile per block; LDS stride 65 (bf16) is conflict-free for
// both the row writes and the column reads (odd stride spreads banks).
// ---------------------------------------------------------------------------
__global__ __launch_bounds__(256) void transpose_v(
    const float* __restrict__ qkv, unsigned short* __restrict__ vt) {
    __shared__ unsigned short Ts[64 * 65];
    const int tid = threadIdx.x;
    const int bh = blockIdx.y, n0 = blockIdx.x * 64;
    const int b = bh >> 4, h = bh & 15;
    {
        int r = tid >> 2, s = tid & 3;
        const float* src =
            qkv + ((size_t)(b * N_ + n0 + r) * 3 + 2) * DIM_ + h * 64 + s * 16;
#pragma unroll
        for (int i = 0; i < 16; ++i) Ts[r * 65 + s * 16 + i] = f2bf(src[i]);
    }
    __syncthreads();
    {
        int d = tid >> 2, ks = tid & 3;
        __align__(16) unsigned short tmp[16];
#pragma unroll
        for (int i = 0; i < 16; ++i) tmp[i] = Ts[(ks * 16 + i) * 65 + d];
        unsigned short* dst = vt + (size_t)(bh * 64 + d) * N_ + n0 + ks * 16;
        *(int4*)dst = *(const int4*)&tmp[0];
        *(int4*)(dst + 8) = *(const int4*)&tmp[8];
    }
}

// ---------------------------------------------------------------------------
// MFMA flash attention. q,k bf16 (B,H,N,D); vt bf16 (B,H,D,N); mask int32
// (B,1,N,N) nonzero=masked; ao fp32 (B,H,N,D). Block=256 (4 waves), 64-row
// Q tile per block, 64-key tiles streamed. 16x16x32 bf16 MFMA.
// Layouts (verified m89/m120): A/B frag[m|n=lane&15][k=quad*8+j],
// C/D [row=quad*4+reg][col=lane&15].
// ---------------------------------------------------------------------------
__global__ __launch_bounds__(256) void flash_attn_mfma(
    const unsigned short* __restrict__ q, const unsigned short* __restrict__ k,
    const unsigned short* __restrict__ vt, const int* __restrict__ mask,
    float* __restrict__ ao) {
    __shared__ unsigned short Qs[64 * 64];
    __shared__ unsigned short Ks[64 * 64];
    __shared__ unsigned short Vts[64 * 64];
    __shared__ float Ss[64 * 65];
    __shared__ float m_s[64], l_s[64], al_s[64];

    const int tid = threadIdx.x;
    const int wave = tid >> 6, lane = tid & 63;
    const int quad = lane >> 4, lcol = lane & 15;
    const int bh = blockIdx.y;  // b*H + h
    const int b = bh >> 4;
    const int q0 = blockIdx.x * 64;
    const int* mask_b = mask + (size_t)b * N_ * N_;

    // ---- stage Q (contiguous 8 KB tile), init softmax state ----
    {
        const char* qg = (const char*)(q + (size_t)(bh * N_ + q0) * 64);
#pragma unroll
        for (int c = 0; c < 2; ++c) {
            int ofs = wave * 2048 + c * 1024 + lane * 16;
            gl_lds16(qg + ofs, (char*)Qs + wave * 2048 + c * 1024);
        }
    }
    if (tid < 64) {
        m_s[tid] = -3.0e38f;
        l_s[tid] = 0.f;
    }
    __syncthreads();  // Q visible (barrier drains vmcnt)

    bf16x8 aq[2];
    aq[0] = *(const bf16x8*)&Qs[(wave * 16 + lcol) * 64 + quad * 8];
    aq[1] = *(const bf16x8*)&Qs[(wave * 16 + lcol) * 64 + 32 + quad * 8];

    f32x4 oacc[4];
#pragma unroll
    for (int i = 0; i < 4; ++i) oacc[i] = (f32x4){0.f, 0.f, 0.f, 0.f};

    for (int k0 = 0; k0 < N_; k0 += 64) {
        __syncthreads();  // previous iteration's LDS reads complete

        // ---- stage K tile (contiguous) and V^T tile (strided rows) ----
        {
            const char* kg = (const char*)(k + (size_t)(bh * N_ + k0) * 64);
#pragma unroll
            for (int c = 0; c < 2; ++c) {
                int lin = wave * 2048 + c * 1024;
                gl_lds16(kg + lin + lane * 16, (char*)Ks + lin);
            }
            const char* vg = (const char*)vt;
#pragma unroll
            for (int c = 0; c < 2; ++c) {
                int lin = wave * 2048 + c * 1024;
                int myofs = lin + lane * 16;
                int d = myofs >> 7;          // 128 B per d-row
                int koffb = myofs & 127;
                const char* g = vg + ((size_t)(bh * 64 + d) * N_ + k0) * 2 + koffb;
                gl_lds16(g, (char*)Vts + lin);
            }
        }
        __syncthreads();  // staging complete

        // ---- S = Q K^T via MFMA, mask, write to LDS ----
        f32x4 sacc[4];
#pragma unroll
        for (int i = 0; i < 4; ++i) sacc[i] = (f32x4){0.f, 0.f, 0.f, 0.f};
#pragma unroll
        for (int n0 = 0; n0 < 4; ++n0) {
#pragma unroll
            for (int d0 = 0; d0 < 2; ++d0) {
                bf16x8 bk = *(const bf16x8*)&Ks[(n0 * 16 + lcol) * 64 + d0 * 32 + quad * 8];
                sacc[n0] = __builtin_amdgcn_mfma_f32_16x16x32_bf16(
                    aq[d0], bk, sacc[n0], 0, 0, 0);
            }
        }
#pragma unroll
        for (int n0 = 0; n0 < 4; ++n0) {
            const int col = n0 * 16 + lcol;
#pragma unroll
            for (int reg = 0; reg < 4; ++reg) {
                int row = wave * 16 + quad * 4 + reg;
                int mv = mask_b[(size_t)(q0 + row) * N_ + k0 + col];
                Ss[row * 65 + col] = mv ? -1e30f : sacc[n0][reg];
            }
        }
        __syncthreads();  // S tile complete

        // ---- online softmax: 4 threads per row, 16 cols each ----
        {
            int srow = tid >> 2, seg = tid & 3;
            float vals[16];
            float mloc = -3.0e38f;
#pragma unroll
            for (int c = 0; c < 16; ++c) {
                vals[c] = Ss[srow * 65 + seg * 16 + c];
                mloc = fmaxf(mloc, vals[c]);
            }
            mloc = fmaxf(mloc, __shfl_xor(mloc, 1, 4));
            mloc = fmaxf(mloc, __shfl_xor(mloc, 2, 4));
            float mold = m_s[srow];
            float mnew = fmaxf(mold, mloc);
            float ssum = 0.f;
#pragma unroll
            for (int c = 0; c < 16; ++c) {
                float p = __expf(vals[c] - mnew);
                Ss[srow * 65 + seg * 16 + c] = p;
                ssum += p;
            }
            ssum += __shfl_xor(ssum, 1, 4);
            ssum += __shfl_xor(ssum, 2, 4);
            if (seg == 0) {
                float alpha = __expf(mold - mnew);
                m_s[srow] = mnew;
                al_s[srow] = alpha;
                l_s[srow] = l_s[srow] * alpha + ssum;
            }
        }
        __syncthreads();  // P + alpha ready

        // ---- O = O*alpha + P V via MFMA ----
        float al[4];
#pragma unroll
        for (int reg = 0; reg < 4; ++reg)
            al[reg] = al_s[wave * 16 + quad * 4 + reg];
#pragma unroll
        for (int n0 = 0; n0 < 4; ++n0)
#pragma unroll
            for (int reg = 0; reg < 4; ++reg) oacc[n0][reg] *= al[reg];

#pragma unroll
        for (int k2 = 0; k2 < 2; ++k2) {
            const float* srow = &Ss[(wave * 16 + lcol) * 65 + k2 * 32 + quad * 8];
            ushort8 pt;
#pragma unroll
            for (int j = 0; j < 8; ++j) pt[j] = f2bf(srow[j]);
            bf16x8 pf = __builtin_bit_cast(bf16x8, pt);
#pragma unroll
            for (int n0 = 0; n0 < 4; ++n0) {
                bf16x8 vf = *(const bf16x8*)&Vts[(n0 * 16 + lcol) * 64 + k2 * 32 + quad * 8];
                oacc[n0] = __builtin_amdgcn_mfma_f32_16x16x32_bf16(
                    pf, vf, oacc[n0], 0, 0, 0);
            }
        }
    }

    // ---- epilogue: divide by l, store fp32 (B,H,N,D) ----
    float invl[4];
#pragma unroll
    for (int reg = 0; reg < 4; ++reg)
        invl[reg] = 1.f / l_s[wave * 16 + quad * 4 + reg];
#pragma unroll
    for (int n0 = 0; n0 < 4; ++n0)
#pragma unroll
        for (int reg = 0; reg < 4; ++reg)
            ao[(size_t)(bh * N_ + q0 + wave * 16 + quad * 4 + reg) * 64 +
               n0 * 16 + lcol] = oacc[n0][reg] * invl[reg];
}

// ---------------------------------------------------------------------------
extern "C" void kernel_launch(void* const* d_in, const int* in_sizes, int n_in,
                              void* d_out, int out_size, void* d_ws,
                              size_t ws_size, hipStream_t stream) {
    const float* x     = (const float*)d_in[0];
    const int*   mask  = (const int*)d_in[1];
    const float* qkv_w = (const float*)d_in[2];
    const float* qnw   = (const float*)d_in[3];
    const float* qnb   = (const float*)d_in[4];
    const float* knw   = (const float*)d_in[5];
    const float* knb   = (const float*)d_in[6];
    const float* pw    = (const float*)d_in[7];
    const float* pb    = (const float*)d_in[8];
    float* out = (float*)d_out;

    // workspace layout
    float* qkv = (float*)d_ws;                                   // 12.58M fp32
    unsigned short* qbuf =
        (unsigned short*)((char*)d_ws + (size_t)12582912 * 4);   // 4.19M bf16
    unsigned short* kbuf = qbuf + (size_t)4194304;
    unsigned short* vt   = kbuf + (size_t)4194304;
    float* ao = qkv;  // alias: qkv fp32 dead after norm/transpose

    // 1) qkv = x @ qkv_w^T (fp32)
    gemm_nt<0, 0><<<dim3(3072 / 64, 4096 / 64), 256, 0, stream>>>(
        x, qkv_w, nullptr, qkv, B_ * N_, 3 * DIM_, DIM_);

    // 2) layernorm q,k -> bf16 (B,H,N,D)
    qkv_norm_split<<<dim3((B_ * N_ * 2 * H_) / 4), 256, 0, stream>>>(
        qkv, qnw, qnb, knw, knb, qbuf, kbuf);

    // 2b) v -> bf16 transposed (B,H,D,N)
    transpose_v<<<dim3(N_ / 64, B_ * H_), 256, 0, stream>>>(qkv, vt);

    // 3) masked flash attention (MFMA) -> ao fp32 (B,H,N,D)
    flash_attn_mfma<<<dim3(N_ / 64, B_ * H_), 256, 0, stream>>>(qbuf, kbuf, vt,
                                                                mask, ao);

    // 4) out = ao(gathered) @ proj_w^T + proj_b (fp32)
    gemm_nt<1, 1><<<dim3(DIM_ / 64, 4096 / 64), 256, 0, stream>>>(
        ao, pw, pb, out, B_ * N_, DIM_, DIM_);
}

// Round 3
// 365.849 us; speedup vs baseline: 4.3297x; 2.6980x over previous
//
#include <hip/hip_runtime.h>
#include <hip/hip_bf16.h>
#include <math.h>

#define B_    2
#define N_    2048
#define DIM_  1024
#define H_    16
#define HD_   64
#define EPS_  1e-5f
#define SCALE_ 0.125f   // HD_^-0.5

typedef __attribute__((ext_vector_type(8))) __bf16 bf16x8;
typedef __attribute__((ext_vector_type(8))) unsigned short ushort8;
typedef __attribute__((ext_vector_type(4))) float f32x4;

__device__ __forceinline__ unsigned short f2bf(float x) {
    unsigned u = __builtin_bit_cast(unsigned, x);
    u += 0x7fff + ((u >> 16) & 1);   // RNE
    return (unsigned short)(u >> 16);
}
__device__ __forceinline__ float bf2f(unsigned short x) {
    unsigned u = ((unsigned)x) << 16;
    return __builtin_bit_cast(float, u);
}

__device__ __forceinline__ void gl_lds16(const void* g, void* l) {
    __builtin_amdgcn_global_load_lds(
        (const __attribute__((address_space(1))) void*)g,
        (__attribute__((address_space(3))) void*)l, 16, 0, 0);
}

// ---------------------------------------------------------------------------
// fp32 -> bf16 cast, 8 elems/thread. n must be divisible by 2048.
// ---------------------------------------------------------------------------
__global__ __launch_bounds__(256) void cast_f32_bf16(
    const float* __restrict__ in, unsigned short* __restrict__ out, int n) {
    int i = (blockIdx.x * 256 + threadIdx.x) * 8;
    float4 v0 = *(const float4*)(in + i);
    float4 v1 = *(const float4*)(in + i + 4);
    ushort8 r;
    r[0] = f2bf(v0.x); r[1] = f2bf(v0.y); r[2] = f2bf(v0.z); r[3] = f2bf(v0.w);
    r[4] = f2bf(v1.x); r[5] = f2bf(v1.y); r[6] = f2bf(v1.z); r[7] = f2bf(v1.w);
    *(ushort8*)(out + i) = r;
}

// ---------------------------------------------------------------------------
// bf16 MFMA NT GEMM (m97 structure): C[M,N] = A[M,K] * B[N,K]^T (+bias).
// 128x128 tile, BK=32, 256 threads (4 waves, 2x2 wave grid, 4x4 MFMA frags
// per wave). global_load_lds width=16 staging into unpadded LDS.
// A/B frag [m|n=lane&15][k=quad*8+j]; C/D [row=quad*4+reg][col=lane&15].
// ---------------------------------------------------------------------------
template <int WITH_BIAS, int OUT_BF16>
__global__ __launch_bounds__(256) void gemm_bt_mfma(
    const unsigned short* __restrict__ A, const unsigned short* __restrict__ Bw,
    const float* __restrict__ bias, void* __restrict__ Cout, int M, int Ncols,
    int K) {
    __shared__ unsigned short As[128 * 32];
    __shared__ unsigned short Bs[128 * 32];
    const int tid = threadIdx.x;
    const int wave = tid >> 6, lane = tid & 63;
    const int quad = lane >> 4, lcol = lane & 15;
    const int wr = wave >> 1, wc = wave & 1;
    const int row0 = blockIdx.y * 128, col0 = blockIdx.x * 128;

    f32x4 acc[4][4];
#pragma unroll
    for (int i = 0; i < 4; ++i)
#pragma unroll
        for (int j = 0; j < 4; ++j) acc[i][j] = (f32x4){0.f, 0.f, 0.f, 0.f};

    for (int k0 = 0; k0 < K; k0 += 32) {
        __syncthreads();  // previous iteration's LDS reads done
#pragma unroll
        for (int c = 0; c < 2; ++c) {
            int base = wave * 2048 + c * 1024;   // LDS byte base (wave-uniform)
            int myofs = base + lane * 16;        // this lane's byte offset
            int r = myofs >> 6;                  // 64 B per row (32 bf16)
            int kb = myofs & 63;
            gl_lds16((const char*)A + ((size_t)(row0 + r) * K + k0) * 2 + kb,
                     (char*)As + base);
            gl_lds16((const char*)Bw + ((size_t)(col0 + r) * K + k0) * 2 + kb,
                     (char*)Bs + base);
        }
        __syncthreads();  // staging complete (barrier drains vmcnt)

        bf16x8 af[4], bfr[4];
#pragma unroll
        for (int i = 0; i < 4; ++i) {
            af[i] = *(const bf16x8*)&As[(wr * 64 + i * 16 + lcol) * 32 + quad * 8];
            bfr[i] = *(const bf16x8*)&Bs[(wc * 64 + i * 16 + lcol) * 32 + quad * 8];
        }
#pragma unroll
        for (int i = 0; i < 4; ++i)
#pragma unroll
            for (int j = 0; j < 4; ++j)
                acc[i][j] = __builtin_amdgcn_mfma_f32_16x16x32_bf16(
                    af[i], bfr[j], acc[i][j], 0, 0, 0);
    }

#pragma unroll
    for (int i = 0; i < 4; ++i) {
#pragma unroll
        for (int j = 0; j < 4; ++j) {
            int col = col0 + wc * 64 + j * 16 + lcol;
            float bv = WITH_BIAS ? bias[col] : 0.f;
#pragma unroll
            for (int reg = 0; reg < 4; ++reg) {
                int row = row0 + wr * 64 + i * 16 + quad * 4 + reg;
                float v = acc[i][j][reg] + bv;
                if (OUT_BF16)
                    ((unsigned short*)Cout)[(size_t)row * Ncols + col] = f2bf(v);
                else
                    ((float*)Cout)[(size_t)row * Ncols + col] = v;
            }
        }
    }
}

// ---------------------------------------------------------------------------
// LayerNorm q,k (fp32 math, bf16 in) -> bf16 (B,H,N,D). One wave per
// (b,n,t,h), t in {0,1}. q pre-scaled by D^-0.5.
// ---------------------------------------------------------------------------
__global__ __launch_bounds__(256) void qkv_norm_split(
    const unsigned short* __restrict__ qkv, const float* __restrict__ qw,
    const float* __restrict__ qb, const float* __restrict__ kw,
    const float* __restrict__ kb, unsigned short* __restrict__ qo,
    unsigned short* __restrict__ ko) {
    int wid = blockIdx.x * 4 + (threadIdx.x >> 6);  // ((b*N+n)*2+t)*H + h
    int lane = threadIdx.x & 63;
    int h = wid & 15;
    int t = (wid >> 4) & 1;
    int bn = wid >> 5;
    int n = bn & (N_ - 1);
    int b = bn >> 11;
    float val = bf2f(qkv[((size_t)bn * 3 + t) * DIM_ + h * 64 + lane]);
    size_t oidx = ((size_t)(b * H_ + h) * N_ + n) * 64 + lane;
    float s = val;
#pragma unroll
    for (int off = 32; off > 0; off >>= 1) s += __shfl_xor(s, off);
    float mu = s * (1.f / 64.f);
    float d = val - mu;
    float s2 = d * d;
#pragma unroll
    for (int off = 32; off > 0; off >>= 1) s2 += __shfl_xor(s2, off);
    float r = rsqrtf(s2 * (1.f / 64.f) + EPS_);
    if (t == 0) {
        qo[oidx] = f2bf((d * r * qw[lane] + qb[lane]) * SCALE_);
    } else {
        ko[oidx] = f2bf(d * r * kw[lane] + kb[lane]);
    }
}

// ---------------------------------------------------------------------------
// Extract V (bf16) from qkv, write transposed (B,H,D,N).
// ---------------------------------------------------------------------------
__global__ __launch_bounds__(256) void transpose_v(
    const unsigned short* __restrict__ qkv, unsigned short* __restrict__ vt) {
    __shared__ unsigned short Ts[64 * 65];
    const int tid = threadIdx.x;
    const int bh = blockIdx.y, n0 = blockIdx.x * 64;
    const int b = bh >> 4, h = bh & 15;
    {
        int r = tid >> 2, s = tid & 3;
        const unsigned short* src =
            qkv + ((size_t)(b * N_ + n0 + r) * 3 + 2) * DIM_ + h * 64 + s * 16;
#pragma unroll
        for (int i = 0; i < 16; ++i) Ts[r * 65 + s * 16 + i] = src[i];
    }
    __syncthreads();
    {
        int d = tid >> 2, ks = tid & 3;
        __align__(16) unsigned short tmp[16];
#pragma unroll
        for (int i = 0; i < 16; ++i) tmp[i] = Ts[(ks * 16 + i) * 65 + d];
        unsigned short* dst = vt + (size_t)(bh * 64 + d) * N_ + n0 + ks * 16;
        *(int4*)dst = *(const int4*)&tmp[0];
        *(int4*)(dst + 8) = *(const int4*)&tmp[8];
    }
}

// ---------------------------------------------------------------------------
// MFMA flash attention. q,k bf16 (B,H,N,D); vt bf16 (B,H,D,N); mask int32
// nonzero=masked; ao bf16 written in (B,N,C) layout (GEMM2-ready).
// ---------------------------------------------------------------------------
__global__ __launch_bounds__(256) void flash_attn_mfma(
    const unsigned short* __restrict__ q, const unsigned short* __restrict__ k,
    const unsigned short* __restrict__ vt, const int* __restrict__ mask,
    unsigned short* __restrict__ ao) {
    __shared__ unsigned short Qs[64 * 64];
    __shared__ unsigned short Ks[64 * 64];
    __shared__ unsigned short Vts[64 * 64];
    __shared__ float Ss[64 * 65];
    __shared__ float m_s[64], l_s[64], al_s[64];

    const int tid = threadIdx.x;
    const int wave = tid >> 6, lane = tid & 63;
    const int quad = lane >> 4, lcol = lane & 15;
    const int bh = blockIdx.y;  // b*H + h
    const int b = bh >> 4, h = bh & 15;
    const int q0 = blockIdx.x * 64;
    const int* mask_b = mask + (size_t)b * N_ * N_;

    {
        const char* qg = (const char*)(q + (size_t)(bh * N_ + q0) * 64);
#pragma unroll
        for (int c = 0; c < 2; ++c) {
            int ofs = wave * 2048 + c * 1024 + lane * 16;
            gl_lds16(qg + ofs, (char*)Qs + wave * 2048 + c * 1024);
        }
    }
    if (tid < 64) {
        m_s[tid] = -3.0e38f;
        l_s[tid] = 0.f;
    }
    __syncthreads();

    bf16x8 aq[2];
    aq[0] = *(const bf16x8*)&Qs[(wave * 16 + lcol) * 64 + quad * 8];
    aq[1] = *(const bf16x8*)&Qs[(wave * 16 + lcol) * 64 + 32 + quad * 8];

    f32x4 oacc[4];
#pragma unroll
    for (int i = 0; i < 4; ++i) oacc[i] = (f32x4){0.f, 0.f, 0.f, 0.f};

    for (int k0 = 0; k0 < N_; k0 += 64) {
        __syncthreads();
        {
            const char* kg = (const char*)(k + (size_t)(bh * N_ + k0) * 64);
#pragma unroll
            for (int c = 0; c < 2; ++c) {
                int lin = wave * 2048 + c * 1024;
                gl_lds16(kg + lin + lane * 16, (char*)Ks + lin);
            }
            const char* vg = (const char*)vt;
#pragma unroll
            for (int c = 0; c < 2; ++c) {
                int lin = wave * 2048 + c * 1024;
                int myofs = lin + lane * 16;
                int d = myofs >> 7;  // 128 B per d-row
                int koffb = myofs & 127;
                const char* g = vg + ((size_t)(bh * 64 + d) * N_ + k0) * 2 + koffb;
                gl_lds16(g, (char*)Vts + lin);
            }
        }
        __syncthreads();

        // S = Q K^T
        f32x4 sacc[4];
#pragma unroll
        for (int i = 0; i < 4; ++i) sacc[i] = (f32x4){0.f, 0.f, 0.f, 0.f};
#pragma unroll
        for (int n0 = 0; n0 < 4; ++n0) {
#pragma unroll
            for (int d0 = 0; d0 < 2; ++d0) {
                bf16x8 bk =
                    *(const bf16x8*)&Ks[(n0 * 16 + lcol) * 64 + d0 * 32 + quad * 8];
                sacc[n0] = __builtin_amdgcn_mfma_f32_16x16x32_bf16(
                    aq[d0], bk, sacc[n0], 0, 0, 0);
            }
        }
#pragma unroll
        for (int n0 = 0; n0 < 4; ++n0) {
            const int col = n0 * 16 + lcol;
#pragma unroll
            for (int reg = 0; reg < 4; ++reg) {
                int row = wave * 16 + quad * 4 + reg;
                int mv = mask_b[(size_t)(q0 + row) * N_ + k0 + col];
                Ss[row * 65 + col] = mv ? -1e30f : sacc[n0][reg];
            }
        }
        __syncthreads();

        // online softmax: 4 threads/row
        {
            int srow = tid >> 2, seg = tid & 3;
            float vals[16];
            float mloc = -3.0e38f;
#pragma unroll
            for (int c = 0; c < 16; ++c) {
                vals[c] = Ss[srow * 65 + seg * 16 + c];
                mloc = fmaxf(mloc, vals[c]);
            }
            mloc = fmaxf(mloc, __shfl_xor(mloc, 1, 4));
            mloc = fmaxf(mloc, __shfl_xor(mloc, 2, 4));
            float mold = m_s[srow];
            float mnew = fmaxf(mold, mloc);
            float ssum = 0.f;
#pragma unroll
            for (int c = 0; c < 16; ++c) {
                float p = __expf(vals[c] - mnew);
                Ss[srow * 65 + seg * 16 + c] = p;
                ssum += p;
            }
            ssum += __shfl_xor(ssum, 1, 4);
            ssum += __shfl_xor(ssum, 2, 4);
            if (seg == 0) {
                float alpha = __expf(mold - mnew);
                m_s[srow] = mnew;
                al_s[srow] = alpha;
                l_s[srow] = l_s[srow] * alpha + ssum;
            }
        }
        __syncthreads();

        // O = O*alpha + P V
        float al[4];
#pragma unroll
        for (int reg = 0; reg < 4; ++reg)
            al[reg] = al_s[wave * 16 + quad * 4 + reg];
#pragma unroll
        for (int n0 = 0; n0 < 4; ++n0)
#pragma unroll
            for (int reg = 0; reg < 4; ++reg) oacc[n0][reg] *= al[reg];

#pragma unroll
        for (int k2 = 0; k2 < 2; ++k2) {
            const float* srow = &Ss[(wave * 16 + lcol) * 65 + k2 * 32 + quad * 8];
            ushort8 pt;
#pragma unroll
            for (int j = 0; j < 8; ++j) pt[j] = f2bf(srow[j]);
            bf16x8 pf = __builtin_bit_cast(bf16x8, pt);
#pragma unroll
            for (int n0 = 0; n0 < 4; ++n0) {
                bf16x8 vf =
                    *(const bf16x8*)&Vts[(n0 * 16 + lcol) * 64 + k2 * 32 + quad * 8];
                oacc[n0] = __builtin_amdgcn_mfma_f32_16x16x32_bf16(
                    pf, vf, oacc[n0], 0, 0, 0);
            }
        }
    }

    // epilogue: /l, store bf16 in (B,N,C) layout
    float invl[4];
#pragma unroll
    for (int reg = 0; reg < 4; ++reg)
        invl[reg] = 1.f / l_s[wave * 16 + quad * 4 + reg];
#pragma unroll
    for (int n0 = 0; n0 < 4; ++n0)
#pragma unroll
        for (int reg = 0; reg < 4; ++reg) {
            int row = q0 + wave * 16 + quad * 4 + reg;
            ao[((size_t)(b * N_ + row)) * DIM_ + h * 64 + n0 * 16 + lcol] =
                f2bf(oacc[n0][reg] * invl[reg]);
        }
}

// ---------------------------------------------------------------------------
extern "C" void kernel_launch(void* const* d_in, const int* in_sizes, int n_in,
                              void* d_out, int out_size, void* d_ws,
                              size_t ws_size, hipStream_t stream) {
    const float* x     = (const float*)d_in[0];
    const int*   mask  = (const int*)d_in[1];
    const float* qkv_w = (const float*)d_in[2];
    const float* qnw   = (const float*)d_in[3];
    const float* qnb   = (const float*)d_in[4];
    const float* knw   = (const float*)d_in[5];
    const float* knb   = (const float*)d_in[6];
    const float* pw    = (const float*)d_in[7];
    const float* pb    = (const float*)d_in[8];
    float* out = (float*)d_out;

    // workspace layout (bytes) — 64 MB total
    char* ws = (char*)d_ws;
    unsigned short* qkv_bf = (unsigned short*)(ws + 0);          // 25.17 MB
    unsigned short* qbuf   = (unsigned short*)(ws + 25165824);   // 8.39 MB
    unsigned short* kbuf   = (unsigned short*)(ws + 33554432);   // 8.39 MB
    unsigned short* vt     = (unsigned short*)(ws + 41943040);   // 8.39 MB
    unsigned short* x_bf   = (unsigned short*)(ws + 50331648);   // 8.39 MB
    unsigned short* qw_bf  = (unsigned short*)(ws + 58720256);   // 6.29 MB
    unsigned short* pw_bf  = (unsigned short*)(ws + 65011712);   // 2.10 MB
    unsigned short* ao_bnc = x_bf;  // alias: x_bf dead after GEMM1

    // 0) casts
    cast_f32_bf16<<<4194304 / 2048, 256, 0, stream>>>(x, x_bf, 4194304);
    cast_f32_bf16<<<3145728 / 2048, 256, 0, stream>>>(qkv_w, qw_bf, 3145728);
    cast_f32_bf16<<<1048576 / 2048, 256, 0, stream>>>(pw, pw_bf, 1048576);

    // 1) qkv = x @ qkv_w^T (bf16 MFMA, bf16 out)
    gemm_bt_mfma<0, 1><<<dim3(3072 / 128, 4096 / 128), 256, 0, stream>>>(
        x_bf, qw_bf, nullptr, qkv_bf, B_ * N_, 3 * DIM_, DIM_);

    // 2) layernorm q,k -> bf16 (B,H,N,D)
    qkv_norm_split<<<dim3((B_ * N_ * 2 * H_) / 4), 256, 0, stream>>>(
        qkv_bf, qnw, qnb, knw, knb, qbuf, kbuf);

    // 2b) v -> bf16 transposed (B,H,D,N)
    transpose_v<<<dim3(N_ / 64, B_ * H_), 256, 0, stream>>>(qkv_bf, vt);

    // 3) masked flash attention (MFMA) -> ao bf16 (B,N,C)
    flash_attn_mfma<<<dim3(N_ / 64, B_ * H_), 256, 0, stream>>>(qbuf, kbuf, vt,
                                                                mask, ao_bnc);

    // 4) out = ao @ proj_w^T + proj_b (bf16 MFMA, fp32 out)
    gemm_bt_mfma<1, 0><<<dim3(DIM_ / 128, 4096 / 128), 256, 0, stream>>>(
        ao_bnc, pw_bf, pb, out, B_ * N_, DIM_, DIM_);
}

// Round 4
// 363.895 us; speedup vs baseline: 4.3530x; 1.0054x over previous
//
#include <hip/hip_runtime.h>
#include <hip/hip_bf16.h>
#include <math.h>

#define B_    2
#define N_    2048
#define DIM_  1024
#define H_    16
#define HD_   64
#define EPS_  1e-5f
#define SCALE_ 0.125f   // HD_^-0.5

typedef __attribute__((ext_vector_type(8))) __bf16 bf16x8;
typedef __attribute__((ext_vector_type(8))) unsigned short ushort8;
typedef __attribute__((ext_vector_type(4))) float f32x4;

__device__ __forceinline__ unsigned short f2bf(float x) {
    unsigned u = __builtin_bit_cast(unsigned, x);
    u += 0x7fff + ((u >> 16) & 1);   // RNE
    return (unsigned short)(u >> 16);
}
__device__ __forceinline__ float bf2f(unsigned short x) {
    unsigned u = ((unsigned)x) << 16;
    return __builtin_bit_cast(float, u);
}

__device__ __forceinline__ void gl_lds16(const void* g, void* l) {
    __builtin_amdgcn_global_load_lds(
        (const __attribute__((address_space(1))) void*)g,
        (__attribute__((address_space(3))) void*)l, 16, 0, 0);
}

// ---------------------------------------------------------------------------
// fp32 -> bf16 cast, 8 elems/thread.
// ---------------------------------------------------------------------------
__global__ __launch_bounds__(256) void cast_f32_bf16(
    const float* __restrict__ in, unsigned short* __restrict__ out, int n) {
    int i = (blockIdx.x * 256 + threadIdx.x) * 8;
    float4 v0 = *(const float4*)(in + i);
    float4 v1 = *(const float4*)(in + i + 4);
    ushort8 r;
    r[0] = f2bf(v0.x); r[1] = f2bf(v0.y); r[2] = f2bf(v0.z); r[3] = f2bf(v0.w);
    r[4] = f2bf(v1.x); r[5] = f2bf(v1.y); r[6] = f2bf(v1.z); r[7] = f2bf(v1.w);
    *(ushort8*)(out + i) = r;
}

// ---------------------------------------------------------------------------
// Pack int32 mask (B,N,N) -> bitmask (B,N,N/64) uint64. One wave per word.
// ---------------------------------------------------------------------------
__global__ __launch_bounds__(256) void pack_mask(
    const int* __restrict__ mask, unsigned long long* __restrict__ bm) {
    int w = blockIdx.x * 4 + (threadIdx.x >> 6);
    int lane = threadIdx.x & 63;
    int mv = mask[(size_t)w * 64 + lane];
    unsigned long long bits = __ballot(mv != 0);
    if (lane == 0) bm[w] = bits;
}

// ---------------------------------------------------------------------------
// bf16 MFMA NT GEMM (m97 structure): C[M,N] = A[M,K] * B[N,K]^T (+bias).
// ---------------------------------------------------------------------------
template <int WITH_BIAS, int OUT_BF16>
__global__ __launch_bounds__(256) void gemm_bt_mfma(
    const unsigned short* __restrict__ A, const unsigned short* __restrict__ Bw,
    const float* __restrict__ bias, void* __restrict__ Cout, int M, int Ncols,
    int K) {
    __shared__ unsigned short As[128 * 32];
    __shared__ unsigned short Bs[128 * 32];
    const int tid = threadIdx.x;
    const int wave = tid >> 6, lane = tid & 63;
    const int quad = lane >> 4, lcol = lane & 15;
    const int wr = wave >> 1, wc = wave & 1;
    const int row0 = blockIdx.y * 128, col0 = blockIdx.x * 128;

    f32x4 acc[4][4];
#pragma unroll
    for (int i = 0; i < 4; ++i)
#pragma unroll
        for (int j = 0; j < 4; ++j) acc[i][j] = (f32x4){0.f, 0.f, 0.f, 0.f};

    for (int k0 = 0; k0 < K; k0 += 32) {
        __syncthreads();
#pragma unroll
        for (int c = 0; c < 2; ++c) {
            int base = wave * 2048 + c * 1024;
            int myofs = base + lane * 16;
            int r = myofs >> 6;
            int kb = myofs & 63;
            gl_lds16((const char*)A + ((size_t)(row0 + r) * K + k0) * 2 + kb,
                     (char*)As + base);
            gl_lds16((const char*)Bw + ((size_t)(col0 + r) * K + k0) * 2 + kb,
                     (char*)Bs + base);
        }
        __syncthreads();

        bf16x8 af[4], bfr[4];
#pragma unroll
        for (int i = 0; i < 4; ++i) {
            af[i] = *(const bf16x8*)&As[(wr * 64 + i * 16 + lcol) * 32 + quad * 8];
            bfr[i] = *(const bf16x8*)&Bs[(wc * 64 + i * 16 + lcol) * 32 + quad * 8];
        }
#pragma unroll
        for (int i = 0; i < 4; ++i)
#pragma unroll
            for (int j = 0; j < 4; ++j)
                acc[i][j] = __builtin_amdgcn_mfma_f32_16x16x32_bf16(
                    af[i], bfr[j], acc[i][j], 0, 0, 0);
    }

#pragma unroll
    for (int i = 0; i < 4; ++i) {
#pragma unroll
        for (int j = 0; j < 4; ++j) {
            int col = col0 + wc * 64 + j * 16 + lcol;
            float bv = WITH_BIAS ? bias[col] : 0.f;
#pragma unroll
            for (int reg = 0; reg < 4; ++reg) {
                int row = row0 + wr * 64 + i * 16 + quad * 4 + reg;
                float v = acc[i][j][reg] + bv;
                if (OUT_BF16)
                    ((unsigned short*)Cout)[(size_t)row * Ncols + col] = f2bf(v);
                else
                    ((float*)Cout)[(size_t)row * Ncols + col] = v;
            }
        }
    }
}

// ---------------------------------------------------------------------------
// LayerNorm q,k (fp32 math, bf16 in) -> bf16 (B,H,N,D).
// ---------------------------------------------------------------------------
__global__ __launch_bounds__(256) void qkv_norm_split(
    const unsigned short* __restrict__ qkv, const float* __restrict__ qw,
    const float* __restrict__ qb, const float* __restrict__ kw,
    const float* __restrict__ kb, unsigned short* __restrict__ qo,
    unsigned short* __restrict__ ko) {
    int wid = blockIdx.x * 4 + (threadIdx.x >> 6);
    int lane = threadIdx.x & 63;
    int h = wid & 15;
    int t = (wid >> 4) & 1;
    int bn = wid >> 5;
    int n = bn & (N_ - 1);
    int b = bn >> 11;
    float val = bf2f(qkv[((size_t)bn * 3 + t) * DIM_ + h * 64 + lane]);
    size_t oidx = ((size_t)(b * H_ + h) * N_ + n) * 64 + lane;
    float s = val;
#pragma unroll
    for (int off = 32; off > 0; off >>= 1) s += __shfl_xor(s, off);
    float mu = s * (1.f / 64.f);
    float d = val - mu;
    float s2 = d * d;
#pragma unroll
    for (int off = 32; off > 0; off >>= 1) s2 += __shfl_xor(s2, off);
    float r = rsqrtf(s2 * (1.f / 64.f) + EPS_);
    if (t == 0) {
        qo[oidx] = f2bf((d * r * qw[lane] + qb[lane]) * SCALE_);
    } else {
        ko[oidx] = f2bf(d * r * kw[lane] + kb[lane]);
    }
}

// ---------------------------------------------------------------------------
// Extract V (bf16) from qkv, write transposed (B,H,D,N).
// ---------------------------------------------------------------------------
__global__ __launch_bounds__(256) void transpose_v(
    const unsigned short* __restrict__ qkv, unsigned short* __restrict__ vt) {
    __shared__ unsigned short Ts[64 * 65];
    const int tid = threadIdx.x;
    const int bh = blockIdx.y, n0 = blockIdx.x * 64;
    const int b = bh >> 4, h = bh & 15;
    {
        int r = tid >> 2, s = tid & 3;
        const unsigned short* src =
            qkv + ((size_t)(b * N_ + n0 + r) * 3 + 2) * DIM_ + h * 64 + s * 16;
#pragma unroll
        for (int i = 0; i < 16; ++i) Ts[r * 65 + s * 16 + i] = src[i];
    }
    __syncthreads();
    {
        int d = tid >> 2, ks = tid & 3;
        __align__(16) unsigned short tmp[16];
#pragma unroll
        for (int i = 0; i < 16; ++i) tmp[i] = Ts[(ks * 16 + i) * 65 + d];
        unsigned short* dst = vt + (size_t)(bh * 64 + d) * N_ + n0 + ks * 16;
        *(int4*)dst = *(const int4*)&tmp[0];
        *(int4*)(dst + 8) = *(const int4*)&tmp[8];
    }
}

// ---------------------------------------------------------------------------
// MFMA flash attention v2: 128-row Q tile, in-register online softmax,
// wave-private LDS P buffers, bitmask mask.
// q,k bf16 (B,H,N,D); vt bf16 (B,H,D,N); bm uint64 (B,N,N/64);
// ao bf16 written in (B,N,C) layout.
// Wave w owns rows w*32..w*32+31 (2 row-tiles of 16).
// A/B frag [m|n=lane&15][k=quad*8+j]; C/D [row=quad*4+reg][col=lane&15].
// A row's 64 cols live in the 16 lanes of quad=(row>>2)&3: shfl_xor 1/2/4/8.
// ---------------------------------------------------------------------------
__global__ __launch_bounds__(256) void flash_attn_mfma2(
    const unsigned short* __restrict__ q, const unsigned short* __restrict__ k,
    const unsigned short* __restrict__ vt,
    const unsigned long long* __restrict__ bm, unsigned short* __restrict__ ao) {
    __shared__ unsigned short Qs[128 * 64];      // 16 KB
    __shared__ unsigned short Ks[64 * 64];       // 8 KB
    __shared__ unsigned short Vts[64 * 64];      // 8 KB
    __shared__ unsigned short Ps[4][32 * 72];    // 18 KB, wave-private, stride 72

    const int tid = threadIdx.x;
    const int wave = tid >> 6, lane = tid & 63;
    const int quad = lane >> 4, lcol = lane & 15;
    const int bh = blockIdx.y, b = bh >> 4, h = bh & 15;
    const int q0 = blockIdx.x * 128;

    // ---- stage Q (16 KB contiguous) ----
    {
        const char* qg = (const char*)(q + (size_t)(bh * N_ + q0) * 64);
#pragma unroll
        for (int c = 0; c < 4; ++c) {
            int base = wave * 4096 + c * 1024;
            gl_lds16(qg + base + lane * 16, (char*)Qs + base);
        }
    }
    __syncthreads();

    bf16x8 aq[2][2];
#pragma unroll
    for (int rt = 0; rt < 2; ++rt)
#pragma unroll
        for (int d0 = 0; d0 < 2; ++d0)
            aq[rt][d0] = *(const bf16x8*)&Qs[(wave * 32 + rt * 16 + lcol) * 64 +
                                             d0 * 32 + quad * 8];

    f32x4 oacc[2][4];
    float m_r[2][4], l_r[2][4];
#pragma unroll
    for (int rt = 0; rt < 2; ++rt) {
#pragma unroll
        for (int n0 = 0; n0 < 4; ++n0) oacc[rt][n0] = (f32x4){0.f, 0.f, 0.f, 0.f};
#pragma unroll
        for (int reg = 0; reg < 4; ++reg) {
            m_r[rt][reg] = -3.0e38f;
            l_r[rt][reg] = 0.f;
        }
    }

    // bitmask row base for this thread's 8 rows
    const size_t bmrow[2] = {
        ((size_t)b * N_ + q0 + wave * 32 + quad * 4) * 32,
        ((size_t)b * N_ + q0 + wave * 32 + 16 + quad * 4) * 32};

    for (int k0 = 0; k0 < N_; k0 += 64) {
        __syncthreads();  // previous iteration's K/V LDS reads done
        {
            const char* kg = (const char*)(k + (size_t)(bh * N_ + k0) * 64);
#pragma unroll
            for (int c = 0; c < 2; ++c) {
                int lin = wave * 2048 + c * 1024;
                gl_lds16(kg + lin + lane * 16, (char*)Ks + lin);
            }
#pragma unroll
            for (int c = 0; c < 2; ++c) {
                int lin = wave * 2048 + c * 1024;
                int myofs = lin + lane * 16;
                int d = myofs >> 7;  // 128 B per d-row
                int kb = myofs & 127;
                gl_lds16((const char*)vt + ((size_t)(bh * 64 + d) * N_ + k0) * 2 + kb,
                         (char*)Vts + lin);
            }
        }
        // mask words (independent of staging; 16-lane-uniform broadcast loads)
        unsigned long long mw[2][4];
        const int widx = k0 >> 6;
#pragma unroll
        for (int rt = 0; rt < 2; ++rt)
#pragma unroll
            for (int reg = 0; reg < 4; ++reg)
                mw[rt][reg] = bm[bmrow[rt] + (size_t)reg * 32 + widx];
        __syncthreads();  // staging complete

        // ---- S = Q K^T ----
        f32x4 sacc[2][4];
#pragma unroll
        for (int rt = 0; rt < 2; ++rt)
#pragma unroll
            for (int n0 = 0; n0 < 4; ++n0) sacc[rt][n0] = (f32x4){0.f, 0.f, 0.f, 0.f};
#pragma unroll
        for (int n0 = 0; n0 < 4; ++n0) {
#pragma unroll
            for (int d0 = 0; d0 < 2; ++d0) {
                bf16x8 bk =
                    *(const bf16x8*)&Ks[(n0 * 16 + lcol) * 64 + d0 * 32 + quad * 8];
#pragma unroll
                for (int rt = 0; rt < 2; ++rt)
                    sacc[rt][n0] = __builtin_amdgcn_mfma_f32_16x16x32_bf16(
                        aq[rt][d0], bk, sacc[rt][n0], 0, 0, 0);
            }
        }

        // ---- mask + in-register online softmax + P -> wave-private LDS ----
#pragma unroll
        for (int rt = 0; rt < 2; ++rt) {
#pragma unroll
            for (int reg = 0; reg < 4; ++reg) {
                unsigned lo = (unsigned)mw[rt][reg];
                unsigned hi = (unsigned)(mw[rt][reg] >> 32);
                float mloc = -3.0e38f;
#pragma unroll
                for (int n0 = 0; n0 < 4; ++n0) {
                    unsigned word = (n0 < 2) ? lo : hi;
                    unsigned bit = (word >> ((n0 & 1) * 16 + lcol)) & 1u;
                    float s = bit ? -1e30f : sacc[rt][n0][reg];
                    sacc[rt][n0][reg] = s;
                    mloc = fmaxf(mloc, s);
                }
                mloc = fmaxf(mloc, __shfl_xor(mloc, 1));
                mloc = fmaxf(mloc, __shfl_xor(mloc, 2));
                mloc = fmaxf(mloc, __shfl_xor(mloc, 4));
                mloc = fmaxf(mloc, __shfl_xor(mloc, 8));
                float mold = m_r[rt][reg];
                float mnew = fmaxf(mold, mloc);
                float alpha = __expf(mold - mnew);
                m_r[rt][reg] = mnew;
                float rs = 0.f;
                int prow = rt * 16 + quad * 4 + reg;
#pragma unroll
                for (int n0 = 0; n0 < 4; ++n0) {
                    float p = __expf(sacc[rt][n0][reg] - mnew);
                    rs += p;
                    Ps[wave][prow * 72 + n0 * 16 + lcol] = f2bf(p);
                }
                rs += __shfl_xor(rs, 1);
                rs += __shfl_xor(rs, 2);
                rs += __shfl_xor(rs, 4);
                rs += __shfl_xor(rs, 8);
                l_r[rt][reg] = l_r[rt][reg] * alpha + rs;
                // rescale O accumulators for this row
#pragma unroll
                for (int n0 = 0; n0 < 4; ++n0) oacc[rt][n0][reg] *= alpha;
            }
        }

        // ---- O += P V  (P from wave-private LDS: no barrier needed) ----
#pragma unroll
        for (int k2 = 0; k2 < 2; ++k2) {
            bf16x8 pf[2];
#pragma unroll
            for (int rt = 0; rt < 2; ++rt)
                pf[rt] = *(const bf16x8*)&Ps[wave][(rt * 16 + lcol) * 72 +
                                                   k2 * 32 + quad * 8];
#pragma unroll
            for (int n0 = 0; n0 < 4; ++n0) {
                bf16x8 vf =
                    *(const bf16x8*)&Vts[(n0 * 16 + lcol) * 64 + k2 * 32 + quad * 8];
#pragma unroll
                for (int rt = 0; rt < 2; ++rt)
                    oacc[rt][n0] = __builtin_amdgcn_mfma_f32_16x16x32_bf16(
                        pf[rt], vf, oacc[rt][n0], 0, 0, 0);
            }
        }
    }

    // ---- epilogue: /l, store bf16 (B,N,C) ----
#pragma unroll
    for (int rt = 0; rt < 2; ++rt)
#pragma unroll
        for (int reg = 0; reg < 4; ++reg) {
            float inv = 1.f / l_r[rt][reg];
            int row = q0 + wave * 32 + rt * 16 + quad * 4 + reg;
            unsigned short* dst = ao + ((size_t)(b * N_ + row)) * DIM_ + h * 64;
#pragma unroll
            for (int n0 = 0; n0 < 4; ++n0)
                dst[n0 * 16 + lcol] = f2bf(oacc[rt][n0][reg] * inv);
        }
}

// ---------------------------------------------------------------------------
extern "C" void kernel_launch(void* const* d_in, const int* in_sizes, int n_in,
                              void* d_out, int out_size, void* d_ws,
                              size_t ws_size, hipStream_t stream) {
    const float* x     = (const float*)d_in[0];
    const int*   mask  = (const int*)d_in[1];
    const float* qkv_w = (const float*)d_in[2];
    const float* qnw   = (const float*)d_in[3];
    const float* qnb   = (const float*)d_in[4];
    const float* knw   = (const float*)d_in[5];
    const float* knb   = (const float*)d_in[6];
    const float* pw    = (const float*)d_in[7];
    const float* pb    = (const float*)d_in[8];
    float* out = (float*)d_out;

    // workspace layout (bytes) — 67.1 MB total (same footprint as round 3)
    char* ws = (char*)d_ws;
    unsigned short* qkv_bf = (unsigned short*)(ws + 0);          // 25.17 MB
    unsigned short* qbuf   = (unsigned short*)(ws + 25165824);   // 8.39 MB
    unsigned short* kbuf   = (unsigned short*)(ws + 33554432);   // 8.39 MB
    unsigned short* vt     = (unsigned short*)(ws + 41943040);   // 8.39 MB
    unsigned short* x_bf   = (unsigned short*)(ws + 50331648);   // 8.39 MB
    unsigned short* qw_bf  = (unsigned short*)(ws + 58720256);   // 6.29 MB
    unsigned short* pw_bf  = (unsigned short*)(ws + 65011712);   // 2.10 MB
    unsigned short* ao_bnc = x_bf;  // alias: x_bf dead after GEMM1
    // bitmask (1 MB) aliases qkv_bf: written only after norm+transpose
    unsigned long long* bmask = (unsigned long long*)(ws + 0);

    // 0) casts
    cast_f32_bf16<<<4194304 / 2048, 256, 0, stream>>>(x, x_bf, 4194304);
    cast_f32_bf16<<<3145728 / 2048, 256, 0, stream>>>(qkv_w, qw_bf, 3145728);
    cast_f32_bf16<<<1048576 / 2048, 256, 0, stream>>>(pw, pw_bf, 1048576);

    // 1) qkv = x @ qkv_w^T (bf16 MFMA, bf16 out)
    gemm_bt_mfma<0, 1><<<dim3(3072 / 128, 4096 / 128), 256, 0, stream>>>(
        x_bf, qw_bf, nullptr, qkv_bf, B_ * N_, 3 * DIM_, DIM_);

    // 2) layernorm q,k -> bf16 (B,H,N,D)
    qkv_norm_split<<<dim3((B_ * N_ * 2 * H_) / 4), 256, 0, stream>>>(
        qkv_bf, qnw, qnb, knw, knb, qbuf, kbuf);

    // 2b) v -> bf16 transposed (B,H,D,N)
    transpose_v<<<dim3(N_ / 64, B_ * H_), 256, 0, stream>>>(qkv_bf, vt);

    // 2c) pack mask to bits (qkv_bf region is dead now)
    pack_mask<<<(B_ * N_ * (N_ / 64)) / 4, 256, 0, stream>>>(mask, bmask);

    // 3) masked flash attention v2 -> ao bf16 (B,N,C)
    flash_attn_mfma2<<<dim3(N_ / 128, B_ * H_), 256, 0, stream>>>(
        qbuf, kbuf, vt, bmask, ao_bnc);

    // 4) out = ao @ proj_w^T + proj_b (bf16 MFMA, fp32 out)
    gemm_bt_mfma<1, 0><<<dim3(DIM_ / 128, 4096 / 128), 256, 0, stream>>>(
        ao_bnc, pw_bf, pb, out, B_ * N_, DIM_, DIM_);
}

// Round 5
// 304.662 us; speedup vs baseline: 5.1993x; 1.1944x over previous
//
#include <hip/hip_runtime.h>
#include <hip/hip_bf16.h>
#include <math.h>

#define B_    2
#define N_    2048
#define DIM_  1024
#define H_    16
#define HD_   64
#define EPS_  1e-5f
#define SCALE_ 0.125f   // HD_^-0.5

typedef __attribute__((ext_vector_type(8))) __bf16 bf16x8;
typedef __attribute__((ext_vector_type(8))) unsigned short ushort8;
typedef __attribute__((ext_vector_type(4))) float f32x4;

__device__ __forceinline__ unsigned short f2bf(float x) {
    unsigned u = __builtin_bit_cast(unsigned, x);
    u += 0x7fff + ((u >> 16) & 1);   // RNE
    return (unsigned short)(u >> 16);
}
__device__ __forceinline__ float bf2f(unsigned short x) {
    unsigned u = ((unsigned)x) << 16;
    return __builtin_bit_cast(float, u);
}

__device__ __forceinline__ void gl_lds16(const void* g, void* l) {
    __builtin_amdgcn_global_load_lds(
        (const __attribute__((address_space(1))) void*)g,
        (__attribute__((address_space(3))) void*)l, 16, 0, 0);
}

// ---------------------------------------------------------------------------
// Fused fp32 -> bf16 cast of [x | qkv_w | proj_w] into one contiguous bf16
// region. Block-uniform source selection (boundaries are multiples of 2048).
// ---------------------------------------------------------------------------
__global__ __launch_bounds__(256) void cast_all_bf16(
    const float* __restrict__ x, const float* __restrict__ qkvw,
    const float* __restrict__ pw, unsigned short* __restrict__ out) {
    int i = (blockIdx.x * 256 + threadIdx.x) * 8;
    const float* src;
    if (i < 4194304) src = x + i;
    else if (i < 7340032) src = qkvw + (i - 4194304);
    else src = pw + (i - 7340032);
    float4 v0 = *(const float4*)src;
    float4 v1 = *(const float4*)(src + 4);
    ushort8 r;
    r[0] = f2bf(v0.x); r[1] = f2bf(v0.y); r[2] = f2bf(v0.z); r[3] = f2bf(v0.w);
    r[4] = f2bf(v1.x); r[5] = f2bf(v1.y); r[6] = f2bf(v1.z); r[7] = f2bf(v1.w);
    *(ushort8*)(out + i) = r;
}

// ---------------------------------------------------------------------------
// Pack int32 mask (B,N,N) -> bitmask (B,N,N/64) uint64. One wave per word.
// ---------------------------------------------------------------------------
__global__ __launch_bounds__(256) void pack_mask(
    const int* __restrict__ mask, unsigned long long* __restrict__ bm) {
    int w = blockIdx.x * 4 + (threadIdx.x >> 6);
    int lane = threadIdx.x & 63;
    int mv = mask[(size_t)w * 64 + lane];
    unsigned long long bits = __ballot(mv != 0);
    if (lane == 0) bm[w] = bits;
}

// ---------------------------------------------------------------------------
// bf16 MFMA NT GEMM (m97 structure): C[M,N] = A[M,K] * B[N,K]^T (+bias).
// ---------------------------------------------------------------------------
template <int WITH_BIAS, int OUT_BF16>
__global__ __launch_bounds__(256) void gemm_bt_mfma(
    const unsigned short* __restrict__ A, const unsigned short* __restrict__ Bw,
    const float* __restrict__ bias, void* __restrict__ Cout, int M, int Ncols,
    int K) {
    __shared__ unsigned short As[128 * 32];
    __shared__ unsigned short Bs[128 * 32];
    const int tid = threadIdx.x;
    const int wave = tid >> 6, lane = tid & 63;
    const int quad = lane >> 4, lcol = lane & 15;
    const int wr = wave >> 1, wc = wave & 1;
    const int row0 = blockIdx.y * 128, col0 = blockIdx.x * 128;

    f32x4 acc[4][4];
#pragma unroll
    for (int i = 0; i < 4; ++i)
#pragma unroll
        for (int j = 0; j < 4; ++j) acc[i][j] = (f32x4){0.f, 0.f, 0.f, 0.f};

    for (int k0 = 0; k0 < K; k0 += 32) {
        __syncthreads();
#pragma unroll
        for (int c = 0; c < 2; ++c) {
            int base = wave * 2048 + c * 1024;
            int myofs = base + lane * 16;
            int r = myofs >> 6;
            int kb = myofs & 63;
            gl_lds16((const char*)A + ((size_t)(row0 + r) * K + k0) * 2 + kb,
                     (char*)As + base);
            gl_lds16((const char*)Bw + ((size_t)(col0 + r) * K + k0) * 2 + kb,
                     (char*)Bs + base);
        }
        __syncthreads();

        bf16x8 af[4], bfr[4];
#pragma unroll
        for (int i = 0; i < 4; ++i) {
            af[i] = *(const bf16x8*)&As[(wr * 64 + i * 16 + lcol) * 32 + quad * 8];
            bfr[i] = *(const bf16x8*)&Bs[(wc * 64 + i * 16 + lcol) * 32 + quad * 8];
        }
#pragma unroll
        for (int i = 0; i < 4; ++i)
#pragma unroll
            for (int j = 0; j < 4; ++j)
                acc[i][j] = __builtin_amdgcn_mfma_f32_16x16x32_bf16(
                    af[i], bfr[j], acc[i][j], 0, 0, 0);
    }

#pragma unroll
    for (int i = 0; i < 4; ++i) {
#pragma unroll
        for (int j = 0; j < 4; ++j) {
            int col = col0 + wc * 64 + j * 16 + lcol;
            float bv = WITH_BIAS ? bias[col] : 0.f;
#pragma unroll
            for (int reg = 0; reg < 4; ++reg) {
                int row = row0 + wr * 64 + i * 16 + quad * 4 + reg;
                float v = acc[i][j][reg] + bv;
                if (OUT_BF16)
                    ((unsigned short*)Cout)[(size_t)row * Ncols + col] = f2bf(v);
                else
                    ((float*)Cout)[(size_t)row * Ncols + col] = v;
            }
        }
    }
}

// ---------------------------------------------------------------------------
// LayerNorm q,k (fp32 math, bf16 in) -> bf16 (B,H,N,D).
// ---------------------------------------------------------------------------
__global__ __launch_bounds__(256) void qkv_norm_split(
    const unsigned short* __restrict__ qkv, const float* __restrict__ qw,
    const float* __restrict__ qb, const float* __restrict__ kw,
    const float* __restrict__ kb, unsigned short* __restrict__ qo,
    unsigned short* __restrict__ ko) {
    int wid = blockIdx.x * 4 + (threadIdx.x >> 6);
    int lane = threadIdx.x & 63;
    int h = wid & 15;
    int t = (wid >> 4) & 1;
    int bn = wid >> 5;
    int n = bn & (N_ - 1);
    int b = bn >> 11;
    float val = bf2f(qkv[((size_t)bn * 3 + t) * DIM_ + h * 64 + lane]);
    size_t oidx = ((size_t)(b * H_ + h) * N_ + n) * 64 + lane;
    float s = val;
#pragma unroll
    for (int off = 32; off > 0; off >>= 1) s += __shfl_xor(s, off);
    float mu = s * (1.f / 64.f);
    float d = val - mu;
    float s2 = d * d;
#pragma unroll
    for (int off = 32; off > 0; off >>= 1) s2 += __shfl_xor(s2, off);
    float r = rsqrtf(s2 * (1.f / 64.f) + EPS_);
    if (t == 0) {
        qo[oidx] = f2bf((d * r * qw[lane] + qb[lane]) * SCALE_);
    } else {
        ko[oidx] = f2bf(d * r * kw[lane] + kb[lane]);
    }
}

// ---------------------------------------------------------------------------
// Extract V (bf16) from qkv, write transposed (B,H,D,N).
// ---------------------------------------------------------------------------
__global__ __launch_bounds__(256) void transpose_v(
    const unsigned short* __restrict__ qkv, unsigned short* __restrict__ vt) {
    __shared__ unsigned short Ts[64 * 65];
    const int tid = threadIdx.x;
    const int bh = blockIdx.y, n0 = blockIdx.x * 64;
    const int b = bh >> 4, h = bh & 15;
    {
        int r = tid >> 2, s = tid & 3;
        const unsigned short* src =
            qkv + ((size_t)(b * N_ + n0 + r) * 3 + 2) * DIM_ + h * 64 + s * 16;
#pragma unroll
        for (int i = 0; i < 16; ++i) Ts[r * 65 + s * 16 + i] = src[i];
    }
    __syncthreads();
    {
        int d = tid >> 2, ks = tid & 3;
        __align__(16) unsigned short tmp[16];
#pragma unroll
        for (int i = 0; i < 16; ++i) tmp[i] = Ts[(ks * 16 + i) * 65 + d];
        unsigned short* dst = vt + (size_t)(bh * 64 + d) * N_ + n0 + ks * 16;
        *(int4*)dst = *(const int4*)&tmp[0];
        *(int4*)(dst + 8) = *(const int4*)&tmp[8];
    }
}

// ---------------------------------------------------------------------------
// MFMA flash attention v3: S^T formulation.
// S^T = K Q^T: A=K frag, B=Q frag -> C-layout [key=quad*4+reg][query=lane&15]
// => per-query softmax state (m,l,alpha) is per-LANE scalar; row reduce =
// 15 in-lane ops + 2 shfl (xor16/32). O^T = V^T P^T: A=V^T frag, B=P^T frag
// -> [d=quad*4+reg][query=lane&15].
// K/V staged chunk-major (8 planes of 1 KB) with XOR(2*quad) swizzle so all
// frag ds_read_b128 are <=2-way bank-aliased (free).
// q,k bf16 (B,H,N,D); vt bf16 (B,H,D,N); bm uint64 (B,N,N/64);
// ao bf16 in (B,N,C) layout. Wave w owns queries w*32..w*32+31 (2 ct tiles).
// ---------------------------------------------------------------------------
__global__ __launch_bounds__(256) void flash_attn_mfma3(
    const unsigned short* __restrict__ q, const unsigned short* __restrict__ k,
    const unsigned short* __restrict__ vt,
    const unsigned long long* __restrict__ bm, unsigned short* __restrict__ ao) {
    __shared__ unsigned short Qs[128 * 64];    // 16 KB, row-major
    __shared__ unsigned short Ks[64 * 64];     // 8 KB, 8 planes [d-chunk][key]
    __shared__ unsigned short Vts[64 * 64];    // 8 KB, 8 planes [key-chunk][d]
    __shared__ unsigned short Ps[4][32 * 72];  // 18 KB wave-private [query][key]

    const int tid = threadIdx.x;
    const int wave = tid >> 6, lane = tid & 63;
    const int quad = lane >> 4, lcol = lane & 15;
    const int bh = blockIdx.y, b = bh >> 4, h = bh & 15;
    const int q0 = blockIdx.x * 128;

    // ---- stage Q (16 KB contiguous, row-major) ----
    {
        const char* qg = (const char*)(q + (size_t)(bh * N_ + q0) * 64);
#pragma unroll
        for (int c = 0; c < 4; ++c) {
            int base = wave * 4096 + c * 1024;
            gl_lds16(qg + base + lane * 16, (char*)Qs + base);
        }
    }
    __syncthreads();

    // Q as B-operand frags: [query=lcol][d=quad*8+j], queries wave*32+ct*16+lcol
    bf16x8 bq[2][2];
#pragma unroll
    for (int ct = 0; ct < 2; ++ct)
#pragma unroll
        for (int d0 = 0; d0 < 2; ++d0)
            bq[ct][d0] = *(const bf16x8*)&Qs[(wave * 32 + ct * 16 + lcol) * 64 +
                                             d0 * 32 + quad * 8];

    f32x4 oacc[2][4];  // [ct][dt]: O^T, d=dt*16+quad*4+reg, query=ct*16+lcol
    float m_c[2], l_c[2];
#pragma unroll
    for (int ct = 0; ct < 2; ++ct) {
#pragma unroll
        for (int dt = 0; dt < 4; ++dt) oacc[ct][dt] = (f32x4){0.f, 0.f, 0.f, 0.f};
        m_c[ct] = -3.0e38f;
        l_c[ct] = 0.f;
    }

    // per-query bitmask row pointers (query = this lane's column)
    const unsigned long long* bmq[2];
#pragma unroll
    for (int ct = 0; ct < 2; ++ct)
        bmq[ct] = bm + ((size_t)b * N_ + q0 + wave * 32 + ct * 16 + lcol) * 32;

    const char* kgbase = (const char*)k + (size_t)bh * N_ * 128;
    const char* vtbase = (const char*)vt + (size_t)bh * 64 * N_ * 2;

    for (int k0 = 0; k0 < N_; k0 += 64) {
        __syncthreads();  // prev iteration's Ks/Vts reads done
        // ---- stage K and V^T chunk-major with XOR swizzle ----
#pragma unroll
        for (int ci = 0; ci < 2; ++ci) {
            int c = wave * 2 + ci;
            int swz = (c & 3) * 2;
            int key = lane ^ swz;  // key whose d-chunk c goes to slot `lane`
            gl_lds16(kgbase + (size_t)(k0 + key) * 128 + c * 16,
                     (char*)Ks + c * 1024);
            int d = lane ^ swz;    // d whose key-chunk c goes to slot `lane`
            gl_lds16(vtbase + ((size_t)d * N_ + k0 + c * 8) * 2,
                     (char*)Vts + c * 1024);
        }
        // mask words: one uint64 per query (this lane) per ct
        unsigned long long mw[2];
        const int widx = k0 >> 6;
        mw[0] = bmq[0][widx];
        mw[1] = bmq[1][widx];
        __syncthreads();  // staging complete

        // ---- S^T = K Q^T ----
        f32x4 sacc[2][4];  // [ct][kt]: key=kt*16+quad*4+reg, query=ct*16+lcol
#pragma unroll
        for (int ct = 0; ct < 2; ++ct)
#pragma unroll
            for (int kt = 0; kt < 4; ++kt) sacc[ct][kt] = (f32x4){0.f, 0.f, 0.f, 0.f};
#pragma unroll
        for (int kt = 0; kt < 4; ++kt) {
#pragma unroll
            for (int d0 = 0; d0 < 2; ++d0) {
                int p = d0 * 4 + quad;  // d-chunk plane
                bf16x8 ak = *(const bf16x8*)((const char*)Ks + p * 1024 +
                                             (((kt * 16 + lcol) ^ (quad * 2)) << 4));
#pragma unroll
                for (int ct = 0; ct < 2; ++ct)
                    sacc[ct][kt] = __builtin_amdgcn_mfma_f32_16x16x32_bf16(
                        ak, bq[ct][d0], sacc[ct][kt], 0, 0, 0);
            }
        }

        // ---- mask + online softmax (per-lane query) + P^T -> Ps ----
#pragma unroll
        for (int ct = 0; ct < 2; ++ct) {
            unsigned long long mq = mw[ct] >> (quad * 4);
            float mloc = -3.0e38f;
#pragma unroll
            for (int kt = 0; kt < 4; ++kt) {
                unsigned nib = (unsigned)(mq >> (kt * 16)) & 0xFu;
#pragma unroll
                for (int reg = 0; reg < 4; ++reg) {
                    float s = ((nib >> reg) & 1u) ? -1e30f : sacc[ct][kt][reg];
                    sacc[ct][kt][reg] = s;
                    mloc = fmaxf(mloc, s);
                }
            }
            mloc = fmaxf(mloc, __shfl_xor(mloc, 16));
            mloc = fmaxf(mloc, __shfl_xor(mloc, 32));
            float mold = m_c[ct];
            float mnew = fmaxf(mold, mloc);
            float alpha = __expf(mold - mnew);
            m_c[ct] = mnew;
            float rs = 0.f;
#pragma unroll
            for (int kt = 0; kt < 4; ++kt) {
                unsigned short us[4];
#pragma unroll
                for (int reg = 0; reg < 4; ++reg) {
                    float p = __expf(sacc[ct][kt][reg] - mnew);
                    rs += p;
                    us[reg] = f2bf(p);
                }
                uint2 pk;
                pk.x = us[0] | ((unsigned)us[1] << 16);
                pk.y = us[2] | ((unsigned)us[3] << 16);
                *(uint2*)&Ps[wave][(ct * 16 + lcol) * 72 + kt * 16 + quad * 4] = pk;
            }
            rs += __shfl_xor(rs, 16);
            rs += __shfl_xor(rs, 32);
            l_c[ct] = l_c[ct] * alpha + rs;
#pragma unroll
            for (int dt = 0; dt < 4; ++dt)
#pragma unroll
                for (int reg = 0; reg < 4; ++reg) oacc[ct][dt][reg] *= alpha;
        }

        // ---- O^T += V^T P^T (Ps wave-private: no barrier) ----
#pragma unroll
        for (int k2 = 0; k2 < 2; ++k2) {
            bf16x8 pf[2];
#pragma unroll
            for (int ct = 0; ct < 2; ++ct)
                pf[ct] = *(const bf16x8*)&Ps[wave][(ct * 16 + lcol) * 72 +
                                                   k2 * 32 + quad * 8];
#pragma unroll
            for (int dt = 0; dt < 4; ++dt) {
                int p = k2 * 4 + quad;  // key-chunk plane
                bf16x8 vf = *(const bf16x8*)((const char*)Vts + p * 1024 +
                                             (((dt * 16 + lcol) ^ (quad * 2)) << 4));
#pragma unroll
                for (int ct = 0; ct < 2; ++ct)
                    oacc[ct][dt] = __builtin_amdgcn_mfma_f32_16x16x32_bf16(
                        vf, pf[ct], oacc[ct][dt], 0, 0, 0);
            }
        }
    }

    // ---- epilogue: /l, store bf16 (B,N,C); 4 consecutive d per b64 store ----
#pragma unroll
    for (int ct = 0; ct < 2; ++ct) {
        float inv = 1.f / l_c[ct];
        int row = q0 + wave * 32 + ct * 16 + lcol;
        unsigned short* dst =
            ao + ((size_t)(b * N_ + row)) * DIM_ + h * 64 + quad * 4;
#pragma unroll
        for (int dt = 0; dt < 4; ++dt) {
            unsigned short us[4];
#pragma unroll
            for (int reg = 0; reg < 4; ++reg)
                us[reg] = f2bf(oacc[ct][dt][reg] * inv);
            uint2 pk;
            pk.x = us[0] | ((unsigned)us[1] << 16);
            pk.y = us[2] | ((unsigned)us[3] << 16);
            *(uint2*)(dst + dt * 16) = pk;
        }
    }
}

// ---------------------------------------------------------------------------
extern "C" void kernel_launch(void* const* d_in, const int* in_sizes, int n_in,
                              void* d_out, int out_size, void* d_ws,
                              size_t ws_size, hipStream_t stream) {
    const float* x     = (const float*)d_in[0];
    const int*   mask  = (const int*)d_in[1];
    const float* qkv_w = (const float*)d_in[2];
    const float* qnw   = (const float*)d_in[3];
    const float* qnb   = (const float*)d_in[4];
    const float* knw   = (const float*)d_in[5];
    const float* knb   = (const float*)d_in[6];
    const float* pw    = (const float*)d_in[7];
    const float* pb    = (const float*)d_in[8];
    float* out = (float*)d_out;

    // workspace layout (bytes) — x_bf/qw_bf/pw_bf contiguous for fused cast
    char* ws = (char*)d_ws;
    unsigned short* qkv_bf = (unsigned short*)(ws + 0);          // 25.17 MB
    unsigned short* qbuf   = (unsigned short*)(ws + 25165824);   // 8.39 MB
    unsigned short* kbuf   = (unsigned short*)(ws + 33554432);   // 8.39 MB
    unsigned short* vt     = (unsigned short*)(ws + 41943040);   // 8.39 MB
    unsigned short* x_bf   = (unsigned short*)(ws + 50331648);   // 8.39 MB
    unsigned short* qw_bf  = (unsigned short*)(ws + 58720256);   // 6.29 MB
    unsigned short* pw_bf  = (unsigned short*)(ws + 65011712);   // 2.10 MB
    unsigned short* ao_bnc = x_bf;  // alias: x_bf dead after GEMM1
    unsigned long long* bmask = (unsigned long long*)(ws + 0);  // aliases qkv_bf

    // 0) fused casts -> contiguous [x_bf | qw_bf | pw_bf]
    cast_all_bf16<<<8388608 / 2048, 256, 0, stream>>>(x, qkv_w, pw, x_bf);

    // 1) qkv = x @ qkv_w^T (bf16 MFMA, bf16 out)
    gemm_bt_mfma<0, 1><<<dim3(3072 / 128, 4096 / 128), 256, 0, stream>>>(
        x_bf, qw_bf, nullptr, qkv_bf, B_ * N_, 3 * DIM_, DIM_);

    // 2) layernorm q,k -> bf16 (B,H,N,D)
    qkv_norm_split<<<dim3((B_ * N_ * 2 * H_) / 4), 256, 0, stream>>>(
        qkv_bf, qnw, qnb, knw, knb, qbuf, kbuf);

    // 2b) v -> bf16 transposed (B,H,D,N)
    transpose_v<<<dim3(N_ / 64, B_ * H_), 256, 0, stream>>>(qkv_bf, vt);

    // 2c) pack mask to bits (qkv_bf region is dead now)
    pack_mask<<<(B_ * N_ * (N_ / 64)) / 4, 256, 0, stream>>>(mask, bmask);

    // 3) masked flash attention v3 (S^T) -> ao bf16 (B,N,C)
    flash_attn_mfma3<<<dim3(N_ / 128, B_ * H_), 256, 0, stream>>>(
        qbuf, kbuf, vt, bmask, ao_bnc);

    // 4) out = ao @ proj_w^T + proj_b (bf16 MFMA, fp32 out)
    gemm_bt_mfma<1, 0><<<dim3(DIM_ / 128, 4096 / 128), 256, 0, stream>>>(
        ao_bnc, pw_bf, pb, out, B_ * N_, DIM_, DIM_);
}

// Round 6
// 298.168 us; speedup vs baseline: 5.3126x; 1.0218x over previous
//
#include <hip/hip_runtime.h>
#include <hip/hip_bf16.h>
#include <math.h>

#define B_    2
#define N_    2048
#define DIM_  1024
#define H_    16
#define HD_   64
#define EPS_  1e-5f
#define SCALE_ 0.125f   // HD_^-0.5
#define LOG2E_ 1.4426950408889634f

typedef __attribute__((ext_vector_type(8))) __bf16 bf16x8;
typedef __attribute__((ext_vector_type(8))) unsigned short ushort8;
typedef __attribute__((ext_vector_type(4))) float f32x4;

__device__ __forceinline__ unsigned short f2bf(float x) {
    unsigned u = __builtin_bit_cast(unsigned, x);
    u += 0x7fff + ((u >> 16) & 1);   // RNE
    return (unsigned short)(u >> 16);
}
// pack two floats to bf16x2 with round-half-up (+0x8000) via v_perm:
// result = hi16(b)<<16 | hi16(a)
__device__ __forceinline__ unsigned pk2bf(float a, float b) {
    unsigned ua = __builtin_bit_cast(unsigned, a) + 0x8000u;
    unsigned ub = __builtin_bit_cast(unsigned, b) + 0x8000u;
    return __builtin_amdgcn_perm(ub, ua, 0x07060302);
}

__device__ __forceinline__ void gl_lds16(const void* g, void* l) {
    __builtin_amdgcn_global_load_lds(
        (const __attribute__((address_space(1))) void*)g,
        (__attribute__((address_space(3))) void*)l, 16, 0, 0);
}

// ---------------------------------------------------------------------------
// Fused fp32 -> bf16 cast of [x | qkv_w | proj_w] into one contiguous region.
// ---------------------------------------------------------------------------
__global__ __launch_bounds__(256) void cast_all_bf16(
    const float* __restrict__ x, const float* __restrict__ qkvw,
    const float* __restrict__ pw, unsigned short* __restrict__ out) {
    int i = (blockIdx.x * 256 + threadIdx.x) * 8;
    const float* src;
    if (i < 4194304) src = x + i;
    else if (i < 7340032) src = qkvw + (i - 4194304);
    else src = pw + (i - 7340032);
    float4 v0 = *(const float4*)src;
    float4 v1 = *(const float4*)(src + 4);
    ushort8 r;
    r[0] = f2bf(v0.x); r[1] = f2bf(v0.y); r[2] = f2bf(v0.z); r[3] = f2bf(v0.w);
    r[4] = f2bf(v1.x); r[5] = f2bf(v1.y); r[6] = f2bf(v1.z); r[7] = f2bf(v1.w);
    *(ushort8*)(out + i) = r;
}

// ---------------------------------------------------------------------------
// Pack int32 mask (B,N,N) -> bitmask (B,N,N/64) uint64. One wave per word.
// ---------------------------------------------------------------------------
__global__ __launch_bounds__(256) void pack_mask(
    const int* __restrict__ mask, unsigned long long* __restrict__ bm) {
    int w = blockIdx.x * 4 + (threadIdx.x >> 6);
    int lane = threadIdx.x & 63;
    int mv = mask[(size_t)w * 64 + lane];
    unsigned long long bits = __ballot(mv != 0);
    if (lane == 0) bm[w] = bits;
}

// ---------------------------------------------------------------------------
// GEMM1 + fused LayerNorm epilogue.
// qkv = x_bf @ qkv_w^T  (M=4096, N=3072, K=1024), then per 64-col head span:
//   t=0 (q): LN -> *SCALE*LOG2E -> qbuf (B,H,N,D) bf16
//   t=1 (k): LN -> kbuf (B,H,N,D) bf16
//   t=2 (v): plain bf16 -> vbuf (B,N,H*D)
// A 128-col tile never straddles a t boundary (1024 % 128 == 0); each wave's
// wc-half is exactly one head (64 cols), so LN reduces over j(4) x lcol(16).
// ---------------------------------------------------------------------------
__global__ __launch_bounds__(256) void gemm_qkv_ln(
    const unsigned short* __restrict__ A, const unsigned short* __restrict__ Bw,
    const float* __restrict__ qnw, const float* __restrict__ qnb,
    const float* __restrict__ knw, const float* __restrict__ knb,
    unsigned short* __restrict__ qbuf, unsigned short* __restrict__ kbuf,
    unsigned short* __restrict__ vbuf) {
    const int K = DIM_;
    __shared__ unsigned short As[128 * 32];
    __shared__ unsigned short Bs[128 * 32];
    const int tid = threadIdx.x;
    const int wave = tid >> 6, lane = tid & 63;
    const int quad = lane >> 4, lcol = lane & 15;
    const int wr = wave >> 1, wc = wave & 1;
    const int row0 = blockIdx.y * 128, col0 = blockIdx.x * 128;

    f32x4 acc[4][4];
#pragma unroll
    for (int i = 0; i < 4; ++i)
#pragma unroll
        for (int j = 0; j < 4; ++j) acc[i][j] = (f32x4){0.f, 0.f, 0.f, 0.f};

    for (int k0 = 0; k0 < K; k0 += 32) {
        __syncthreads();
#pragma unroll
        for (int c = 0; c < 2; ++c) {
            int base = wave * 2048 + c * 1024;
            int myofs = base + lane * 16;
            int r = myofs >> 6;
            int kb = myofs & 63;
            gl_lds16((const char*)A + ((size_t)(row0 + r) * K + k0) * 2 + kb,
                     (char*)As + base);
            gl_lds16((const char*)Bw + ((size_t)(col0 + r) * K + k0) * 2 + kb,
                     (char*)Bs + base);
        }
        __syncthreads();

        bf16x8 af[4], bfr[4];
#pragma unroll
        for (int i = 0; i < 4; ++i) {
            af[i] = *(const bf16x8*)&As[(wr * 64 + i * 16 + lcol) * 32 + quad * 8];
            bfr[i] = *(const bf16x8*)&Bs[(wc * 64 + i * 16 + lcol) * 32 + quad * 8];
        }
#pragma unroll
        for (int i = 0; i < 4; ++i)
#pragma unroll
            for (int j = 0; j < 4; ++j)
                acc[i][j] = __builtin_amdgcn_mfma_f32_16x16x32_bf16(
                    af[i], bfr[j], acc[i][j], 0, 0, 0);
    }

    const int colbase = col0 + wc * 64;      // wave-uniform, one head
    const int t = colbase >> 10;             // 0=q, 1=k, 2=v
    const int h = (colbase & 1023) >> 6;

    if (t < 2) {
        const float* wv = (t == 0) ? qnw : knw;
        const float* bv = (t == 0) ? qnb : knb;
        float wreg[4], breg[4];
#pragma unroll
        for (int j = 0; j < 4; ++j) {
            wreg[j] = wv[j * 16 + lcol];
            breg[j] = bv[j * 16 + lcol];
        }
        const float sc = (t == 0) ? (SCALE_ * LOG2E_) : 1.f;
        unsigned short* obase = (t == 0) ? qbuf : kbuf;
#pragma unroll
        for (int i = 0; i < 4; ++i) {
#pragma unroll
            for (int reg = 0; reg < 4; ++reg) {
                int row = row0 + wr * 64 + i * 16 + quad * 4 + reg;
                int bb = row >> 11, n = row & (N_ - 1);
                float v[4];
#pragma unroll
                for (int j = 0; j < 4; ++j) v[j] = acc[i][j][reg];
                float s = v[0] + v[1] + v[2] + v[3];
                s += __shfl_xor(s, 1);
                s += __shfl_xor(s, 2);
                s += __shfl_xor(s, 4);
                s += __shfl_xor(s, 8);
                float mu = s * (1.f / 64.f);
                float d[4], s2 = 0.f;
#pragma unroll
                for (int j = 0; j < 4; ++j) {
                    d[j] = v[j] - mu;
                    s2 += d[j] * d[j];
                }
                s2 += __shfl_xor(s2, 1);
                s2 += __shfl_xor(s2, 2);
                s2 += __shfl_xor(s2, 4);
                s2 += __shfl_xor(s2, 8);
                float r = rsqrtf(s2 * (1.f / 64.f) + EPS_);
                unsigned short* dst =
                    obase + ((size_t)(bb * H_ + h) * N_ + n) * 64 + lcol;
#pragma unroll
                for (int j = 0; j < 4; ++j)
                    dst[j * 16] = f2bf((d[j] * r * wreg[j] + breg[j]) * sc);
            }
        }
    } else {
        const int dcol = colbase & 1023;  // col within (H*D)=1024
#pragma unroll
        for (int i = 0; i < 4; ++i) {
#pragma unroll
            for (int reg = 0; reg < 4; ++reg) {
                int row = row0 + wr * 64 + i * 16 + quad * 4 + reg;
                unsigned short* dst = vbuf + (size_t)row * DIM_ + dcol + lcol;
#pragma unroll
                for (int j = 0; j < 4; ++j)
                    dst[j * 16] = f2bf(acc[i][j][reg]);
            }
        }
    }
}

// ---------------------------------------------------------------------------
// bf16 MFMA NT GEMM (m97 structure): C[M,N] = A[M,K] * B[N,K]^T (+bias).
// Used for the output projection.
// ---------------------------------------------------------------------------
template <int WITH_BIAS, int OUT_BF16>
__global__ __launch_bounds__(256) void gemm_bt_mfma(
    const unsigned short* __restrict__ A, const unsigned short* __restrict__ Bw,
    const float* __restrict__ bias, void* __restrict__ Cout, int M, int Ncols,
    int K) {
    __shared__ unsigned short As[128 * 32];
    __shared__ unsigned short Bs[128 * 32];
    const int tid = threadIdx.x;
    const int wave = tid >> 6, lane = tid & 63;
    const int quad = lane >> 4, lcol = lane & 15;
    const int wr = wave >> 1, wc = wave & 1;
    const int row0 = blockIdx.y * 128, col0 = blockIdx.x * 128;

    f32x4 acc[4][4];
#pragma unroll
    for (int i = 0; i < 4; ++i)
#pragma unroll
        for (int j = 0; j < 4; ++j) acc[i][j] = (f32x4){0.f, 0.f, 0.f, 0.f};

    for (int k0 = 0; k0 < K; k0 += 32) {
        __syncthreads();
#pragma unroll
        for (int c = 0; c < 2; ++c) {
            int base = wave * 2048 + c * 1024;
            int myofs = base + lane * 16;
            int r = myofs >> 6;
            int kb = myofs & 63;
            gl_lds16((const char*)A + ((size_t)(row0 + r) * K + k0) * 2 + kb,
                     (char*)As + base);
            gl_lds16((const char*)Bw + ((size_t)(col0 + r) * K + k0) * 2 + kb,
                     (char*)Bs + base);
        }
        __syncthreads();

        bf16x8 af[4], bfr[4];
#pragma unroll
        for (int i = 0; i < 4; ++i) {
            af[i] = *(const bf16x8*)&As[(wr * 64 + i * 16 + lcol) * 32 + quad * 8];
            bfr[i] = *(const bf16x8*)&Bs[(wc * 64 + i * 16 + lcol) * 32 + quad * 8];
        }
#pragma unroll
        for (int i = 0; i < 4; ++i)
#pragma unroll
            for (int j = 0; j < 4; ++j)
                acc[i][j] = __builtin_amdgcn_mfma_f32_16x16x32_bf16(
                    af[i], bfr[j], acc[i][j], 0, 0, 0);
    }

#pragma unroll
    for (int i = 0; i < 4; ++i) {
#pragma unroll
        for (int j = 0; j < 4; ++j) {
            int col = col0 + wc * 64 + j * 16 + lcol;
            float bv = WITH_BIAS ? bias[col] : 0.f;
#pragma unroll
            for (int reg = 0; reg < 4; ++reg) {
                int row = row0 + wr * 64 + i * 16 + quad * 4 + reg;
                float v = acc[i][j][reg] + bv;
                if (OUT_BF16)
                    ((unsigned short*)Cout)[(size_t)row * Ncols + col] = f2bf(v);
                else
                    ((float*)Cout)[(size_t)row * Ncols + col] = v;
            }
        }
    }
}

// ---------------------------------------------------------------------------
// Extract V (bf16) from vbuf (B,N,H*D), write transposed (B,H,D,N).
// ---------------------------------------------------------------------------
__global__ __launch_bounds__(256) void transpose_v(
    const unsigned short* __restrict__ vbuf, unsigned short* __restrict__ vt) {
    __shared__ unsigned short Ts[64 * 65];
    const int tid = threadIdx.x;
    const int bh = blockIdx.y, n0 = blockIdx.x * 64;
    const int b = bh >> 4, h = bh & 15;
    {
        int r = tid >> 2, s = tid & 3;
        const unsigned short* src =
            vbuf + (size_t)(b * N_ + n0 + r) * DIM_ + h * 64 + s * 16;
#pragma unroll
        for (int i = 0; i < 16; ++i) Ts[r * 65 + s * 16 + i] = src[i];
    }
    __syncthreads();
    {
        int d = tid >> 2, ks = tid & 3;
        __align__(16) unsigned short tmp[16];
#pragma unroll
        for (int i = 0; i < 16; ++i) tmp[i] = Ts[(ks * 16 + i) * 65 + d];
        unsigned short* dst = vt + (size_t)(bh * 64 + d) * N_ + n0 + ks * 16;
        *(int4*)dst = *(const int4*)&tmp[0];
        *(int4*)(dst + 8) = *(const int4*)&tmp[8];
    }
}

// ---------------------------------------------------------------------------
// MFMA flash attention v4: 64-query tile (4 waves x 16 queries), S^T form.
// q is pre-scaled by D^-0.5 * log2(e), so softmax uses exp2.
// S^T = K Q^T -> C[key=quad*4+reg][query=lcol]; per-lane softmax state.
// O^T = V^T P^T -> C[d=quad*4+reg][query=lcol].
// K/V staged chunk-major (8 planes of 1KB) with XOR(2*(c&3)) swizzle.
// LDS 33.8 KB -> 4 blocks/CU; grid 1024 blocks.
// ---------------------------------------------------------------------------
__global__ __launch_bounds__(256) void flash_attn_mfma4(
    const unsigned short* __restrict__ q, const unsigned short* __restrict__ k,
    const unsigned short* __restrict__ vt,
    const unsigned long long* __restrict__ bm, unsigned short* __restrict__ ao) {
    __shared__ unsigned short Qs[64 * 64];     // 8 KB row-major
    __shared__ unsigned short Ks[64 * 64];     // 8 KB, 8 planes [d-chunk][key]
    __shared__ unsigned short Vts[64 * 64];    // 8 KB, 8 planes [key-chunk][d]
    __shared__ unsigned short Ps[4][16 * 72];  // 9 KB wave-private [query][key]

    const int tid = threadIdx.x;
    const int wave = tid >> 6, lane = tid & 63;
    const int quad = lane >> 4, lcol = lane & 15;
    const int bh = blockIdx.y, b = bh >> 4, h = bh & 15;
    const int q0 = blockIdx.x * 64;

    // ---- stage Q (8 KB contiguous) ----
    {
        const char* qg = (const char*)(q + (size_t)(bh * N_ + q0) * 64);
#pragma unroll
        for (int c = 0; c < 2; ++c) {
            int base = wave * 2048 + c * 1024;
            gl_lds16(qg + base + lane * 16, (char*)Qs + base);
        }
    }
    __syncthreads();

    bf16x8 bq[2];
#pragma unroll
    for (int d0 = 0; d0 < 2; ++d0)
        bq[d0] = *(const bf16x8*)&Qs[(wave * 16 + lcol) * 64 + d0 * 32 + quad * 8];

    f32x4 oacc[4];
#pragma unroll
    for (int dt = 0; dt < 4; ++dt) oacc[dt] = (f32x4){0.f, 0.f, 0.f, 0.f};
    float m_c = -3.0e38f, l_c = 0.f;

    const unsigned long long* bmq =
        bm + ((size_t)b * N_ + q0 + wave * 16 + lcol) * 32;
    const char* kgbase = (const char*)k + (size_t)bh * N_ * 128;
    const char* vtbase = (const char*)vt + (size_t)bh * 64 * N_ * 2;

    for (int k0 = 0; k0 < N_; k0 += 64) {
        __syncthreads();  // prev iteration's Ks/Vts reads done
#pragma unroll
        for (int ci = 0; ci < 2; ++ci) {
            int c = wave * 2 + ci;
            int swz = (c & 3) * 2;
            int key = lane ^ swz;
            gl_lds16(kgbase + (size_t)(k0 + key) * 128 + c * 16,
                     (char*)Ks + c * 1024);
            int d = lane ^ swz;
            gl_lds16(vtbase + ((size_t)d * N_ + k0 + c * 8) * 2,
                     (char*)Vts + c * 1024);
        }
        unsigned long long mw = bmq[k0 >> 6];
        __syncthreads();  // staging complete

        // ---- S^T = K Q^T ----
        f32x4 sacc[4];
#pragma unroll
        for (int kt = 0; kt < 4; ++kt) sacc[kt] = (f32x4){0.f, 0.f, 0.f, 0.f};
#pragma unroll
        for (int kt = 0; kt < 4; ++kt) {
#pragma unroll
            for (int d0 = 0; d0 < 2; ++d0) {
                int p = d0 * 4 + quad;
                bf16x8 ak = *(const bf16x8*)((const char*)Ks + p * 1024 +
                                             (((kt * 16 + lcol) ^ (quad * 2)) << 4));
                sacc[kt] = __builtin_amdgcn_mfma_f32_16x16x32_bf16(
                    ak, bq[d0], sacc[kt], 0, 0, 0);
            }
        }

        // ---- mask + online softmax (log2 domain, per-lane query) ----
        unsigned long long mq = mw >> (quad * 4);
        float mloc = -3.0e38f;
#pragma unroll
        for (int kt = 0; kt < 4; ++kt) {
            unsigned nib = (unsigned)(mq >> (kt * 16)) & 0xFu;
#pragma unroll
            for (int reg = 0; reg < 4; ++reg) {
                float s = ((nib >> reg) & 1u) ? -1e30f : sacc[kt][reg];
                sacc[kt][reg] = s;
                mloc = fmaxf(mloc, s);
            }
        }
        mloc = fmaxf(mloc, __shfl_xor(mloc, 16));
        mloc = fmaxf(mloc, __shfl_xor(mloc, 32));
        float mnew = fmaxf(m_c, mloc);
        float alpha = exp2f(m_c - mnew);
        m_c = mnew;
        float rs = 0.f;
#pragma unroll
        for (int kt = 0; kt < 4; ++kt) {
            float p0 = exp2f(sacc[kt][0] - mnew);
            float p1 = exp2f(sacc[kt][1] - mnew);
            float p2 = exp2f(sacc[kt][2] - mnew);
            float p3 = exp2f(sacc[kt][3] - mnew);
            rs += (p0 + p1) + (p2 + p3);
            uint2 pk;
            pk.x = pk2bf(p0, p1);
            pk.y = pk2bf(p2, p3);
            *(uint2*)&Ps[wave][lcol * 72 + kt * 16 + quad * 4] = pk;
        }
        rs += __shfl_xor(rs, 16);
        rs += __shfl_xor(rs, 32);
        l_c = l_c * alpha + rs;
#pragma unroll
        for (int dt = 0; dt < 4; ++dt)
#pragma unroll
            for (int reg = 0; reg < 4; ++reg) oacc[dt][reg] *= alpha;

        // ---- O^T += V^T P^T (Ps wave-private: no barrier) ----
#pragma unroll
        for (int k2 = 0; k2 < 2; ++k2) {
            bf16x8 pf =
                *(const bf16x8*)&Ps[wave][lcol * 72 + k2 * 32 + quad * 8];
#pragma unroll
            for (int dt = 0; dt < 4; ++dt) {
                int p = k2 * 4 + quad;
                bf16x8 vf = *(const bf16x8*)((const char*)Vts + p * 1024 +
                                             (((dt * 16 + lcol) ^ (quad * 2)) << 4));
                oacc[dt] = __builtin_amdgcn_mfma_f32_16x16x32_bf16(
                    vf, pf, oacc[dt], 0, 0, 0);
            }
        }
    }

    // ---- epilogue: /l, store bf16 (B,N,C) ----
    float inv = 1.f / l_c;
    int row = q0 + wave * 16 + lcol;
    unsigned short* dst = ao + ((size_t)(b * N_ + row)) * DIM_ + h * 64 + quad * 4;
#pragma unroll
    for (int dt = 0; dt < 4; ++dt) {
        uint2 pk;
        pk.x = pk2bf(oacc[dt][0] * inv, oacc[dt][1] * inv);
        pk.y = pk2bf(oacc[dt][2] * inv, oacc[dt][3] * inv);
        *(uint2*)(dst + dt * 16) = pk;
    }
}

// ---------------------------------------------------------------------------
extern "C" void kernel_launch(void* const* d_in, const int* in_sizes, int n_in,
                              void* d_out, int out_size, void* d_ws,
                              size_t ws_size, hipStream_t stream) {
    const float* x     = (const float*)d_in[0];
    const int*   mask  = (const int*)d_in[1];
    const float* qkv_w = (const float*)d_in[2];
    const float* qnw   = (const float*)d_in[3];
    const float* qnb   = (const float*)d_in[4];
    const float* knw   = (const float*)d_in[5];
    const float* knb   = (const float*)d_in[6];
    const float* pw    = (const float*)d_in[7];
    const float* pb    = (const float*)d_in[8];
    float* out = (float*)d_out;

    // workspace layout (bytes) — 51.4 MB total
    char* ws = (char*)d_ws;
    unsigned short* x_bf  = (unsigned short*)(ws + 0);          // 8.39 MB
    unsigned short* qw_bf = (unsigned short*)(ws + 8388608);    // 6.29 MB
    unsigned short* pw_bf = (unsigned short*)(ws + 14680064);   // 2.10 MB
    unsigned short* qbuf  = (unsigned short*)(ws + 16777216);   // 8.39 MB
    unsigned short* kbuf  = (unsigned short*)(ws + 25165824);   // 8.39 MB
    unsigned short* vbuf  = (unsigned short*)(ws + 33554432);   // 8.39 MB
    unsigned short* vt    = (unsigned short*)(ws + 41943040);   // 8.39 MB
    unsigned long long* bmask = (unsigned long long*)(ws + 50331648);  // 1 MB
    unsigned short* ao_bnc = vbuf;  // alias: vbuf dead after transpose_v

    // 0) fused casts -> contiguous [x_bf | qw_bf | pw_bf]
    cast_all_bf16<<<8388608 / 2048, 256, 0, stream>>>(x, qkv_w, pw, x_bf);

    // 1) GEMM1 + fused LN epilogue -> qbuf/kbuf (B,H,N,D), vbuf (B,N,HD)
    gemm_qkv_ln<<<dim3(3072 / 128, 4096 / 128), 256, 0, stream>>>(
        x_bf, qw_bf, qnw, qnb, knw, knb, qbuf, kbuf, vbuf);

    // 2) v -> bf16 transposed (B,H,D,N)
    transpose_v<<<dim3(N_ / 64, B_ * H_), 256, 0, stream>>>(vbuf, vt);

    // 2b) pack mask to bits
    pack_mask<<<(B_ * N_ * (N_ / 64)) / 4, 256, 0, stream>>>(mask, bmask);

    // 3) masked flash attention v4 -> ao bf16 (B,N,C)
    flash_attn_mfma4<<<dim3(N_ / 64, B_ * H_), 256, 0, stream>>>(
        qbuf, kbuf, vt, bmask, ao_bnc);

    // 4) out = ao @ proj_w^T + proj_b (bf16 MFMA, fp32 out)
    gemm_bt_mfma<1, 0><<<dim3(DIM_ / 128, 4096 / 128), 256, 0, stream>>>(
        ao_bnc, pw_bf, pb, out, B_ * N_, DIM_, DIM_);
}